// Round 1
// baseline (1193.192 us; speedup 1.0000x reference)
//
#include <hip/hip_runtime.h>
#include <hip/hip_bf16.h>
#include <math.h>

// Problem dims (compile-time constants from the reference)
#define D_MODEL   1024
#define D_INNER   2048
#define NHEADS    32
#define HEADDIM   64
#define D_STATE   64
#define CONV_DIM  2176            // D_INNER + 2*D_STATE
#define D_IN_PROJ 4256            // 2*D_INNER + 2*D_STATE + NHEADS
#define BATCH     2
#define SEQLEN    1024
#define BL        (BATCH * SEQLEN)
#define RMS_EPS   1.1920929e-07f

// ---------------------------------------------------------------------------
// fp32 tiled GEMM, NT layout: C[m,n] = sum_k A[m,k] * B[n,k]
// (A row-major MxK, B row-major NxK -> both loads contiguous along K)
// 128x128 tile, BK=8, 256 threads, 8x8 micro-tile per thread.
// Requires M % 128 == 0 and K % 8 == 0 (true for both call sites); N guarded.
// ---------------------------------------------------------------------------
#define GBM 128
#define GBN 128
#define GBK 8

__global__ __launch_bounds__(256) void gemm_nt_f32(
    const float* __restrict__ A, const float* __restrict__ B,
    float* __restrict__ C, int M, int N, int K, int lda, int ldb, int ldc)
{
    __shared__ float As[GBK][GBM + 4];   // +4 pad keeps float4 alignment, breaks conflicts
    __shared__ float Bs[GBK][GBN + 4];
    const int tid = threadIdx.x;
    const int m0 = blockIdx.y * GBM;
    const int n0 = blockIdx.x * GBN;
    const int tx = tid & 15;             // n-dim 8-wide group
    const int ty = tid >> 4;             // m-dim 8-wide group
    const int lrow = tid >> 1;           // loader: row within tile (0..127)
    const int lcol = (tid & 1) * 4;      // loader: k offset (0 or 4)

    float acc[8][8];
#pragma unroll
    for (int i = 0; i < 8; ++i)
#pragma unroll
        for (int j = 0; j < 8; ++j) acc[i][j] = 0.f;

    const float* aptr = A + (size_t)(m0 + lrow) * lda + lcol;
    const int brow = n0 + lrow;
    const float* bptr = B + (size_t)brow * ldb + lcol;
    const bool bok = (brow < N);

    for (int k0 = 0; k0 < K; k0 += GBK) {
        float4 av = *(const float4*)(aptr + k0);
        float4 bv = make_float4(0.f, 0.f, 0.f, 0.f);
        if (bok) bv = *(const float4*)(bptr + k0);
        As[lcol + 0][lrow] = av.x; As[lcol + 1][lrow] = av.y;
        As[lcol + 2][lrow] = av.z; As[lcol + 3][lrow] = av.w;
        Bs[lcol + 0][lrow] = bv.x; Bs[lcol + 1][lrow] = bv.y;
        Bs[lcol + 2][lrow] = bv.z; Bs[lcol + 3][lrow] = bv.w;
        __syncthreads();
#pragma unroll
        for (int kk = 0; kk < GBK; ++kk) {
            float4 a0 = *(const float4*)&As[kk][ty * 8];
            float4 a1 = *(const float4*)&As[kk][ty * 8 + 4];
            float4 b0 = *(const float4*)&Bs[kk][tx * 8];
            float4 b1 = *(const float4*)&Bs[kk][tx * 8 + 4];
            float a[8] = {a0.x, a0.y, a0.z, a0.w, a1.x, a1.y, a1.z, a1.w};
            float b[8] = {b0.x, b0.y, b0.z, b0.w, b1.x, b1.y, b1.z, b1.w};
#pragma unroll
            for (int i = 0; i < 8; ++i)
#pragma unroll
                for (int j = 0; j < 8; ++j)
                    acc[i][j] = fmaf(a[i], b[j], acc[i][j]);
        }
        __syncthreads();
    }

#pragma unroll
    for (int i = 0; i < 8; ++i) {
        const int m = m0 + ty * 8 + i;
        float* crow = C + (size_t)m * ldc;
#pragma unroll
        for (int jq = 0; jq < 2; ++jq) {
            const int n = n0 + tx * 8 + jq * 4;
            if (n + 3 < N) {
                *(float4*)(crow + n) = make_float4(acc[i][jq * 4 + 0], acc[i][jq * 4 + 1],
                                                   acc[i][jq * 4 + 2], acc[i][jq * 4 + 3]);
            } else {
#pragma unroll
                for (int j = 0; j < 4; ++j)
                    if (n + j < N) crow[n + j] = acc[i][jq * 4 + j];
            }
        }
    }
}

// ---------------------------------------------------------------------------
// dt = softplus(dt_raw + dt_bias), one thread per (m, head)
// ---------------------------------------------------------------------------
__global__ __launch_bounds__(256) void dt_softplus_kernel(
    const float* __restrict__ zx, const float* __restrict__ dt_bias,
    float* __restrict__ dt)
{
    const int idx = blockIdx.x * 256 + threadIdx.x;   // BL*NHEADS
    const int m = idx >> 5;
    const int hd = idx & 31;
    const float v = zx[(size_t)m * D_IN_PROJ + (D_INNER + CONV_DIM) + hd] + dt_bias[hd];
    dt[idx] = (v > 20.f) ? v : log1pf(expf(v));
}

// ---------------------------------------------------------------------------
// causal depthwise conv (D_CONV=4) + silu, one thread per (m, channel)
// ---------------------------------------------------------------------------
__global__ __launch_bounds__(256) void conv_silu_kernel(
    const float* __restrict__ zx, const float* __restrict__ conv_w,
    const float* __restrict__ conv_b, float* __restrict__ xc)
{
    const int idx = blockIdx.x * 256 + threadIdx.x;   // BL*CONV_DIM (exact grid)
    const int m = idx / CONV_DIM;
    const int c = idx - m * CONV_DIM;
    const int l = m & (SEQLEN - 1);
    float acc = conv_b[c];
    const float* base = zx + (size_t)m * D_IN_PROJ + D_INNER + c;
#pragma unroll
    for (int k = 0; k < 4; ++k) {
        const int ll = l - 3 + k;
        if (ll >= 0)
            acc = fmaf(base[(ptrdiff_t)(k - 3) * D_IN_PROJ], conv_w[c * 4 + k], acc);
    }
    xc[idx] = acc / (1.f + expf(-acc));   // silu
}

// ---------------------------------------------------------------------------
// Sequential SSM scan. One block per (batch, head); 4 waves split D_STATE
// (wave w owns n in [w*16, w*16+16)), lane = p (HEADDIM). State in registers.
// Per step: h[p][n] = h*dA + (dt*x[p])*B[n];  y[p] = sum_n h[p][n]*C[n] + D*x[p]
// Next row's x/B/C prefetched into registers during compute.
// ---------------------------------------------------------------------------
__global__ __launch_bounds__(256) void ssm_scan_kernel(
    const float* __restrict__ xc, const float* __restrict__ dt,
    const float* __restrict__ A_log, const float* __restrict__ D_param,
    float* __restrict__ y)
{
    const int bh = blockIdx.x;
    const int b = bh >> 5;
    const int hd = bh & 31;
    const int tid = threadIdx.x;
    const int lane = tid & 63;   // p index
    const int w = tid >> 6;      // n-quarter

    const float A = -expf(A_log[hd]);
    const float Dp = D_param[hd];

    __shared__ float sB[2][64];
    __shared__ float sC[2][64];
    __shared__ float sX[2][64];
    __shared__ float sP[4][64];

    float h[16];
#pragma unroll
    for (int j = 0; j < 16; ++j) h[j] = 0.f;

    const float* rbase = xc + (size_t)b * SEQLEN * CONV_DIM;
    const float* dtp = dt + (size_t)b * SEQLEN * NHEADS + hd;
    float* yp = y + (size_t)b * SEQLEN * D_INNER + hd * HEADDIM + lane;

    // prefetch row t=0
    float pre = 0.f;
    if (w == 0)      pre = rbase[D_INNER + lane];
    else if (w == 1) pre = rbase[D_INNER + D_STATE + lane];
    else if (w == 2) pre = rbase[hd * HEADDIM + lane];
    float dtv = dtp[0];
    int buf = 0;

    for (int t = 0; t < SEQLEN; ++t) {
        if (w == 0)      sB[buf][lane] = pre;
        else if (w == 1) sC[buf][lane] = pre;
        else if (w == 2) sX[buf][lane] = pre;
        const float dcur = dtv;
        if (t + 1 < SEQLEN) {   // prefetch next row while computing this one
            const float* r = rbase + (size_t)(t + 1) * CONV_DIM;
            if (w == 0)      pre = r[D_INNER + lane];
            else if (w == 1) pre = r[D_INNER + D_STATE + lane];
            else if (w == 2) pre = r[hd * HEADDIM + lane];
            dtv = dtp[(t + 1) * NHEADS];
        }
        __syncthreads();
        const float dA = expf(dcur * A);
        const float c0 = dcur * sX[buf][lane];
        float a0 = 0.f, a1 = 0.f;
#pragma unroll
        for (int j = 0; j < 16; j += 2) {
            const int n = w * 16 + j;
            h[j]     = fmaf(h[j],     dA, c0 * sB[buf][n]);
            a0       = fmaf(h[j],     sC[buf][n],     a0);
            h[j + 1] = fmaf(h[j + 1], dA, c0 * sB[buf][n + 1]);
            a1       = fmaf(h[j + 1], sC[buf][n + 1], a1);
        }
        sP[w][lane] = a0 + a1;
        __syncthreads();
        if (w == 0) {
            yp[(size_t)t * D_INNER] =
                sP[0][lane] + sP[1][lane] + sP[2][lane] + sP[3][lane] + Dp * sX[buf][lane];
        }
        buf ^= 1;
    }
}

// ---------------------------------------------------------------------------
// RMSNorm (over D_INNER) * norm_w * silu(z), one block per row
// ---------------------------------------------------------------------------
__global__ __launch_bounds__(256) void rms_gate_kernel(
    const float* __restrict__ y, const float* __restrict__ zx,
    const float* __restrict__ norm_w, float* __restrict__ out)
{
    const int m = blockIdx.x;
    const int tid = threadIdx.x;
    const float* yr = y + (size_t)m * D_INNER;
    const float* zr = zx + (size_t)m * D_IN_PROJ;   // z = cols [0, D_INNER)

    float4 v0 = *(const float4*)(yr + tid * 8);
    float4 v1 = *(const float4*)(yr + tid * 8 + 4);
    float yv[8] = {v0.x, v0.y, v0.z, v0.w, v1.x, v1.y, v1.z, v1.w};
    float ss = 0.f;
#pragma unroll
    for (int j = 0; j < 8; ++j) ss += yv[j] * yv[j];
#pragma unroll
    for (int off = 32; off > 0; off >>= 1) ss += __shfl_xor(ss, off, 64);
    __shared__ float sred[4];
    if ((tid & 63) == 0) sred[tid >> 6] = ss;
    __syncthreads();
    const float tot = sred[0] + sred[1] + sred[2] + sred[3];
    const float inv = rsqrtf(tot * (1.f / D_INNER) + RMS_EPS);

    float4 z0 = *(const float4*)(zr + tid * 8);
    float4 z1 = *(const float4*)(zr + tid * 8 + 4);
    float zv[8] = {z0.x, z0.y, z0.z, z0.w, z1.x, z1.y, z1.z, z1.w};
    const float* nw = norm_w + tid * 8;
    float o[8];
#pragma unroll
    for (int j = 0; j < 8; ++j) {
        const float zz = zv[j];
        const float sig = 1.f / (1.f + expf(-zz));
        o[j] = yv[j] * inv * nw[j] * (zz * sig);
    }
    float* outp = out + (size_t)m * D_INNER + tid * 8;
    *(float4*)(outp)     = make_float4(o[0], o[1], o[2], o[3]);
    *(float4*)(outp + 4) = make_float4(o[4], o[5], o[6], o[7]);
}

// ---------------------------------------------------------------------------
// Workspace layout (floats):
//   zx   : BL*D_IN_PROJ = 8,716,288   (34.9 MB)
//   xc   : BL*CONV_DIM  = 4,456,448   (17.8 MB)  -- reused for gated y later
//   dtb  : BL*NHEADS    =    65,536
//   yssm : BL*D_INNER   = 4,194,304   (16.8 MB)
// total ~69.7 MB
// ---------------------------------------------------------------------------
extern "C" void kernel_launch(void* const* d_in, const int* in_sizes, int n_in,
                              void* d_out, int out_size, void* d_ws, size_t ws_size,
                              hipStream_t stream)
{
    const float* x       = (const float*)d_in[0];
    const float* W_in    = (const float*)d_in[1];
    const float* conv_w  = (const float*)d_in[2];
    const float* conv_b  = (const float*)d_in[3];
    const float* dt_bias = (const float*)d_in[4];
    const float* A_log   = (const float*)d_in[5];
    const float* D_param = (const float*)d_in[6];
    const float* norm_w  = (const float*)d_in[7];
    const float* W_out   = (const float*)d_in[8];
    float* out = (float*)d_out;

    float* ws   = (float*)d_ws;
    float* zx   = ws;
    float* xc   = zx + (size_t)BL * D_IN_PROJ;
    float* dtb  = xc + (size_t)BL * CONV_DIM;
    float* yssm = dtb + (size_t)BL * NHEADS;
    float* yg   = xc;   // reuse conv buffer for gated-normalized y (scan is done by then)

    // 1) in_proj: zx[m,n] = sum_k x[m,k] * W_in[n,k]
    dim3 g1((D_IN_PROJ + GBN - 1) / GBN, BL / GBM);
    gemm_nt_f32<<<g1, 256, 0, stream>>>(x, W_in, zx, BL, D_IN_PROJ, D_MODEL,
                                        D_MODEL, D_MODEL, D_IN_PROJ);
    // 2) dt = softplus(dt_raw + dt_bias)
    dt_softplus_kernel<<<(BL * NHEADS) / 256, 256, 0, stream>>>(zx, dt_bias, dtb);
    // 3) conv1d + silu
    conv_silu_kernel<<<(BL * CONV_DIM) / 256, 256, 0, stream>>>(zx, conv_w, conv_b, xc);
    // 4) sequential SSM scan
    ssm_scan_kernel<<<BATCH * NHEADS, 256, 0, stream>>>(xc, dtb, A_log, D_param, yssm);
    // 5) RMSNorm + silu(z) gate (writes yg over xc region)
    rms_gate_kernel<<<BL, 256, 0, stream>>>(yssm, zx, norm_w, yg);
    // 6) out_proj: out[m,d] = sum_j yg[m,j] * W_out[d,j]
    dim3 g2(D_MODEL / GBN, BL / GBM);
    gemm_nt_f32<<<g2, 256, 0, stream>>>(yg, W_out, out, BL, D_MODEL, D_INNER,
                                        D_INNER, D_INNER, D_MODEL);
}

// Round 2
// 710.975 us; speedup vs baseline: 1.6782x; 1.6782x over previous
//
#include <hip/hip_runtime.h>
#include <hip/hip_bf16.h>
#include <math.h>

// Problem dims (compile-time constants from the reference)
#define D_MODEL   1024
#define D_INNER   2048
#define NHEADS    32
#define HEADDIM   64
#define D_STATE   64
#define CONV_DIM  2176            // D_INNER + 2*D_STATE
#define D_IN_PROJ 4256            // 2*D_INNER + 2*D_STATE + NHEADS
#define BATCH     2
#define SEQLEN    1024
#define BL        (BATCH * SEQLEN)
#define RMS_EPS   1.1920929e-07f

// Chunked-scan parameters
#define QCHUNK 64                 // chunk length
#define NC     (SEQLEN / QCHUNK)  // 16 chunks per batch

// ---------------------------------------------------------------------------
// fp32 tiled GEMM, NT layout: C[m,n] = sum_k A[m,k] * B[n,k]
// ---------------------------------------------------------------------------
#define GBM 128
#define GBN 128
#define GBK 8

__global__ __launch_bounds__(256) void gemm_nt_f32(
    const float* __restrict__ A, const float* __restrict__ B,
    float* __restrict__ C, int M, int N, int K, int lda, int ldb, int ldc)
{
    __shared__ float As[GBK][GBM + 4];
    __shared__ float Bs[GBK][GBN + 4];
    const int tid = threadIdx.x;
    const int m0 = blockIdx.y * GBM;
    const int n0 = blockIdx.x * GBN;
    const int tx = tid & 15;
    const int ty = tid >> 4;
    const int lrow = tid >> 1;
    const int lcol = (tid & 1) * 4;

    float acc[8][8];
#pragma unroll
    for (int i = 0; i < 8; ++i)
#pragma unroll
        for (int j = 0; j < 8; ++j) acc[i][j] = 0.f;

    const float* aptr = A + (size_t)(m0 + lrow) * lda + lcol;
    const int brow = n0 + lrow;
    const float* bptr = B + (size_t)brow * ldb + lcol;
    const bool bok = (brow < N);

    for (int k0 = 0; k0 < K; k0 += GBK) {
        float4 av = *(const float4*)(aptr + k0);
        float4 bv = make_float4(0.f, 0.f, 0.f, 0.f);
        if (bok) bv = *(const float4*)(bptr + k0);
        As[lcol + 0][lrow] = av.x; As[lcol + 1][lrow] = av.y;
        As[lcol + 2][lrow] = av.z; As[lcol + 3][lrow] = av.w;
        Bs[lcol + 0][lrow] = bv.x; Bs[lcol + 1][lrow] = bv.y;
        Bs[lcol + 2][lrow] = bv.z; Bs[lcol + 3][lrow] = bv.w;
        __syncthreads();
#pragma unroll
        for (int kk = 0; kk < GBK; ++kk) {
            float4 a0 = *(const float4*)&As[kk][ty * 8];
            float4 a1 = *(const float4*)&As[kk][ty * 8 + 4];
            float4 b0 = *(const float4*)&Bs[kk][tx * 8];
            float4 b1 = *(const float4*)&Bs[kk][tx * 8 + 4];
            float a[8] = {a0.x, a0.y, a0.z, a0.w, a1.x, a1.y, a1.z, a1.w};
            float b[8] = {b0.x, b0.y, b0.z, b0.w, b1.x, b1.y, b1.z, b1.w};
#pragma unroll
            for (int i = 0; i < 8; ++i)
#pragma unroll
                for (int j = 0; j < 8; ++j)
                    acc[i][j] = fmaf(a[i], b[j], acc[i][j]);
        }
        __syncthreads();
    }

#pragma unroll
    for (int i = 0; i < 8; ++i) {
        const int m = m0 + ty * 8 + i;
        float* crow = C + (size_t)m * ldc;
#pragma unroll
        for (int jq = 0; jq < 2; ++jq) {
            const int n = n0 + tx * 8 + jq * 4;
            if (n + 3 < N) {
                *(float4*)(crow + n) = make_float4(acc[i][jq * 4 + 0], acc[i][jq * 4 + 1],
                                                   acc[i][jq * 4 + 2], acc[i][jq * 4 + 3]);
            } else {
#pragma unroll
                for (int j = 0; j < 4; ++j)
                    if (n + j < N) crow[n + j] = acc[i][jq * 4 + j];
            }
        }
    }
}

// ---------------------------------------------------------------------------
// dt = softplus(dt_raw + dt_bias), written TRANSPOSED: dtt[b][h][l]
// ---------------------------------------------------------------------------
__global__ __launch_bounds__(256) void dt_softplus_kernel(
    const float* __restrict__ zx, const float* __restrict__ dt_bias,
    float* __restrict__ dtt)
{
    const int idx = blockIdx.x * 256 + threadIdx.x;   // BL*NHEADS
    const int m = idx >> 5;          // row (b*SEQLEN + l)
    const int hd = idx & 31;
    const int b = m >> 10;
    const int l = m & (SEQLEN - 1);
    const float v = zx[(size_t)m * D_IN_PROJ + (D_INNER + CONV_DIM) + hd] + dt_bias[hd];
    const float sp = (v > 20.f) ? v : log1pf(expf(v));
    dtt[((size_t)b * NHEADS + hd) * SEQLEN + l] = sp;
}

// ---------------------------------------------------------------------------
// causal depthwise conv (D_CONV=4) + silu
// ---------------------------------------------------------------------------
__global__ __launch_bounds__(256) void conv_silu_kernel(
    const float* __restrict__ zx, const float* __restrict__ conv_w,
    const float* __restrict__ conv_b, float* __restrict__ xc)
{
    const int idx = blockIdx.x * 256 + threadIdx.x;   // BL*CONV_DIM
    const int m = idx / CONV_DIM;
    const int c = idx - m * CONV_DIM;
    const int l = m & (SEQLEN - 1);
    float acc = conv_b[c];
    const float* base = zx + (size_t)m * D_IN_PROJ + D_INNER + c;
#pragma unroll
    for (int k = 0; k < 4; ++k) {
        const int ll = l - 3 + k;
        if (ll >= 0)
            acc = fmaf(base[(ptrdiff_t)(k - 3) * D_IN_PROJ], conv_w[c * 4 + k], acc);
    }
    xc[idx] = acc / (1.f + expf(-acc));
}

// ---------------------------------------------------------------------------
// stage a 64x64 fp32 tile (global row stride = gstride floats) into padded LDS
// ---------------------------------------------------------------------------
__device__ inline void stage_tile64(const float* __restrict__ g, size_t gstride,
                                    float (*lds)[QCHUNK + 1], int tid)
{
    const int r = tid >> 2;
    const int q = (tid & 3) * 16;
    const float* src = g + (size_t)r * gstride + q;
    float* dst = &lds[r][q];
#pragma unroll
    for (int k = 0; k < 4; ++k) {
        float4 v = *(const float4*)(src + k * 4);
        dst[k * 4 + 0] = v.x; dst[k * 4 + 1] = v.y;
        dst[k * 4 + 2] = v.z; dst[k * 4 + 3] = v.w;
    }
}

// ---------------------------------------------------------------------------
// Phase A: per-chunk state  S_intra[n,p] = sum_t exp(cum_end-cum_t)*dt_t*B[t,n]*x[t,p]
// Also stores cumA[b,h,c,t]. One block per (b,h,c).
// ---------------------------------------------------------------------------
__global__ __launch_bounds__(256) void chunk_state_kernel(
    const float* __restrict__ xc, const float* __restrict__ dtt,
    const float* __restrict__ A_log,
    float* __restrict__ Sintra, float* __restrict__ cumA)
{
    const int bid = blockIdx.x;
    const int c = bid & (NC - 1);
    const int h = (bid >> 4) & (NHEADS - 1);
    const int b = bid >> 9;
    const int tid = threadIdx.x;

    __shared__ float sX[QCHUNK][QCHUNK + 1];
    __shared__ float sB[QCHUNK][QCHUNK + 1];
    __shared__ float sw[QCHUNK];

    const float* rbase = xc + ((size_t)b * SEQLEN + c * QCHUNK) * CONV_DIM;
    stage_tile64(rbase + h * HEADDIM, CONV_DIM, sX, tid);
    stage_tile64(rbase + D_INNER, CONV_DIM, sB, tid);

    if (tid < QCHUNK) {
        const float A = -expf(A_log[h]);
        const float dtv = dtt[((size_t)b * NHEADS + h) * SEQLEN + c * QCHUNK + tid];
        float cum = dtv * A;
#pragma unroll
        for (int off = 1; off < 64; off <<= 1) {
            const float o = __shfl_up(cum, off, 64);
            if (tid >= off) cum += o;
        }
        const float cum_end = __shfl(cum, 63, 64);
        sw[tid] = expf(cum_end - cum) * dtv;
        cumA[(size_t)bid * QCHUNK + tid] = cum;
    }
    __syncthreads();

    const int p = tid & 63;
    const int nq = tid >> 6;     // n quarter: n = nq*16 + j
    float acc[16];
#pragma unroll
    for (int j = 0; j < 16; ++j) acc[j] = 0.f;

    for (int t = 0; t < QCHUNK; ++t) {
        const float wx = sw[t] * sX[t][p];
#pragma unroll
        for (int j = 0; j < 16; ++j)
            acc[j] = fmaf(wx, sB[t][nq * 16 + j], acc[j]);
    }

    float* sout = Sintra + (size_t)bid * (D_STATE * HEADDIM);
#pragma unroll
    for (int j = 0; j < 16; ++j)
        sout[(nq * 16 + j) * HEADDIM + p] = acc[j];
}

// ---------------------------------------------------------------------------
// Phase B: sequential inter-chunk recurrence (16 steps), IN-PLACE:
//   SP[c] <- running;  running = S_intra[c] + exp(cum_end[c]) * running
// One block per (b,h); thread owns 16 consecutive state elements.
// ---------------------------------------------------------------------------
__global__ __launch_bounds__(256) void state_pass_kernel(
    float* __restrict__ S, const float* __restrict__ cumA)
{
    const int bh = blockIdx.x;
    const int tid = threadIdx.x;
    const int e0 = tid * 16;

    float run[16];
#pragma unroll
    for (int j = 0; j < 16; ++j) run[j] = 0.f;

    for (int c = 0; c < NC; ++c) {
        const size_t blk = (size_t)(bh * NC + c);
        const float g = expf(cumA[blk * QCHUNK + (QCHUNK - 1)]);
        float* p = S + blk * (D_STATE * HEADDIM) + e0;
        float s[16];
#pragma unroll
        for (int k = 0; k < 4; ++k) {
            float4 v = *(const float4*)(p + k * 4);
            s[k * 4 + 0] = v.x; s[k * 4 + 1] = v.y; s[k * 4 + 2] = v.z; s[k * 4 + 3] = v.w;
        }
#pragma unroll
        for (int k = 0; k < 4; ++k)
            *(float4*)(p + k * 4) = make_float4(run[k * 4 + 0], run[k * 4 + 1],
                                                run[k * 4 + 2], run[k * 4 + 3]);
#pragma unroll
        for (int j = 0; j < 16; ++j)
            run[j] = fmaf(g, run[j], s[j]);
    }
}

// ---------------------------------------------------------------------------
// Phase C: per-chunk output.
//   M[t,s] = (C_t . B_s) * exp(cum_t - cum_s) * dt_s   (s<=t, else 0)
//   Y[t,p] = sum_s M[t,s]*x[s,p] + exp(cum_t)*sum_n C[t,n]*SP[n,p] + D*x[t,p]
// One block per (b,h,c).
// ---------------------------------------------------------------------------
__global__ __launch_bounds__(256) void chunk_output_kernel(
    const float* __restrict__ xc, const float* __restrict__ dtt,
    const float* __restrict__ SP, const float* __restrict__ cumA,
    const float* __restrict__ D_param, float* __restrict__ y)
{
    const int bid = blockIdx.x;
    const int c = bid & (NC - 1);
    const int h = (bid >> 4) & (NHEADS - 1);
    const int b = bid >> 9;
    const int tid = threadIdx.x;

    __shared__ float sBSP[QCHUNK][QCHUNK + 1];   // B, then reused for SP
    __shared__ float sC[QCHUNK][QCHUNK + 1];
    __shared__ float sX[QCHUNK][QCHUNK + 1];
    __shared__ float sM[QCHUNK][QCHUNK + 1];
    __shared__ float scum[QCHUNK];
    __shared__ float sdt[QCHUNK];

    const float* rbase = xc + ((size_t)b * SEQLEN + c * QCHUNK) * CONV_DIM;
    stage_tile64(rbase + h * HEADDIM, CONV_DIM, sX, tid);
    stage_tile64(rbase + D_INNER, CONV_DIM, sBSP, tid);
    stage_tile64(rbase + D_INNER + D_STATE, CONV_DIM, sC, tid);
    if (tid < QCHUNK) {
        scum[tid] = cumA[(size_t)bid * QCHUNK + tid];
        sdt[tid] = dtt[((size_t)b * NHEADS + h) * SEQLEN + c * QCHUNK + tid];
    }
    __syncthreads();

    // --- M[t][s] ---
    {
        const int s = tid & 63;
        const int tq = tid >> 6;
#pragma unroll
        for (int i = 0; i < 16; ++i) {
            const int t = tq * 16 + i;
            float dot = 0.f;
#pragma unroll 8
            for (int n = 0; n < QCHUNK; ++n)
                dot = fmaf(sC[t][n], sBSP[s][n], dot);
            float w = 0.f;
            if (s <= t) w = dot * expf(scum[t] - scum[s]) * sdt[s];
            sM[t][s] = w;
        }
    }
    __syncthreads();

    // overwrite B with SP (state before this chunk)
    stage_tile64(SP + (size_t)bid * (D_STATE * HEADDIM), HEADDIM, sBSP, tid);
    __syncthreads();

    // --- Y ---
    const float Dp = D_param[h];
    const int p = tid & 63;
    const int tq = tid >> 6;
    float* ybase = y + (((size_t)b * SEQLEN + c * QCHUNK) * D_INNER) + h * HEADDIM + p;
#pragma unroll
    for (int i = 0; i < 16; ++i) {
        const int t = tq * 16 + i;
        float a_in = 0.f;
#pragma unroll 8
        for (int s = 0; s < QCHUNK; ++s)
            a_in = fmaf(sM[t][s], sX[s][p], a_in);
        float a_st = 0.f;
#pragma unroll 8
        for (int n = 0; n < QCHUNK; ++n)
            a_st = fmaf(sC[t][n], sBSP[n][p], a_st);
        ybase[(size_t)t * D_INNER] = a_in + expf(scum[t]) * a_st + Dp * sX[t][p];
    }
}

// ---------------------------------------------------------------------------
// RMSNorm * norm_w * silu(z)
// ---------------------------------------------------------------------------
__global__ __launch_bounds__(256) void rms_gate_kernel(
    const float* __restrict__ y, const float* __restrict__ zx,
    const float* __restrict__ norm_w, float* __restrict__ out)
{
    const int m = blockIdx.x;
    const int tid = threadIdx.x;
    const float* yr = y + (size_t)m * D_INNER;
    const float* zr = zx + (size_t)m * D_IN_PROJ;

    float4 v0 = *(const float4*)(yr + tid * 8);
    float4 v1 = *(const float4*)(yr + tid * 8 + 4);
    float yv[8] = {v0.x, v0.y, v0.z, v0.w, v1.x, v1.y, v1.z, v1.w};
    float ss = 0.f;
#pragma unroll
    for (int j = 0; j < 8; ++j) ss += yv[j] * yv[j];
#pragma unroll
    for (int off = 32; off > 0; off >>= 1) ss += __shfl_xor(ss, off, 64);
    __shared__ float sred[4];
    if ((tid & 63) == 0) sred[tid >> 6] = ss;
    __syncthreads();
    const float tot = sred[0] + sred[1] + sred[2] + sred[3];
    const float inv = rsqrtf(tot * (1.f / D_INNER) + RMS_EPS);

    float4 z0 = *(const float4*)(zr + tid * 8);
    float4 z1 = *(const float4*)(zr + tid * 8 + 4);
    float zv[8] = {z0.x, z0.y, z0.z, z0.w, z1.x, z1.y, z1.z, z1.w};
    const float* nw = norm_w + tid * 8;
    float o[8];
#pragma unroll
    for (int j = 0; j < 8; ++j) {
        const float zz = zv[j];
        const float sig = 1.f / (1.f + expf(-zz));
        o[j] = yv[j] * inv * nw[j] * (zz * sig);
    }
    float* outp = out + (size_t)m * D_INNER + tid * 8;
    *(float4*)(outp)     = make_float4(o[0], o[1], o[2], o[3]);
    *(float4*)(outp + 4) = make_float4(o[4], o[5], o[6], o[7]);
}

// ---------------------------------------------------------------------------
// Workspace (floats):
//   zx   : BL*D_IN_PROJ          =  8,716,288
//   xc   : BL*CONV_DIM           =  4,456,448   (reused for gated y)
//   dtt  : BATCH*NHEADS*SEQLEN   =     65,536
//   yssm : BL*D_INNER            =  4,194,304
//   S    : B*H*NC*64*64          =  4,194,304   (Sintra -> SP in place)
//   cumA : B*H*NC*64             =     65,536
// total ~86.8 MB
// ---------------------------------------------------------------------------
extern "C" void kernel_launch(void* const* d_in, const int* in_sizes, int n_in,
                              void* d_out, int out_size, void* d_ws, size_t ws_size,
                              hipStream_t stream)
{
    const float* x       = (const float*)d_in[0];
    const float* W_in    = (const float*)d_in[1];
    const float* conv_w  = (const float*)d_in[2];
    const float* conv_b  = (const float*)d_in[3];
    const float* dt_bias = (const float*)d_in[4];
    const float* A_log   = (const float*)d_in[5];
    const float* D_param = (const float*)d_in[6];
    const float* norm_w  = (const float*)d_in[7];
    const float* W_out   = (const float*)d_in[8];
    float* out = (float*)d_out;

    float* ws   = (float*)d_ws;
    float* zx   = ws;
    float* xc   = zx + (size_t)BL * D_IN_PROJ;
    float* dtt  = xc + (size_t)BL * CONV_DIM;
    float* yssm = dtt + (size_t)BATCH * NHEADS * SEQLEN;
    float* S    = yssm + (size_t)BL * D_INNER;
    float* cumA = S + (size_t)BATCH * NHEADS * NC * D_STATE * HEADDIM;
    float* yg   = xc;

    // 1) in_proj
    dim3 g1((D_IN_PROJ + GBN - 1) / GBN, BL / GBM);
    gemm_nt_f32<<<g1, 256, 0, stream>>>(x, W_in, zx, BL, D_IN_PROJ, D_MODEL,
                                        D_MODEL, D_MODEL, D_IN_PROJ);
    // 2) dt = softplus (transposed layout)
    dt_softplus_kernel<<<(BL * NHEADS) / 256, 256, 0, stream>>>(zx, dt_bias, dtt);
    // 3) conv1d + silu
    conv_silu_kernel<<<(BL * CONV_DIM) / 256, 256, 0, stream>>>(zx, conv_w, conv_b, xc);
    // 4) chunked SSM scan
    chunk_state_kernel<<<BATCH * NHEADS * NC, 256, 0, stream>>>(xc, dtt, A_log, S, cumA);
    state_pass_kernel<<<BATCH * NHEADS, 256, 0, stream>>>(S, cumA);
    chunk_output_kernel<<<BATCH * NHEADS * NC, 256, 0, stream>>>(xc, dtt, S, cumA,
                                                                 D_param, yssm);
    // 5) RMSNorm + gate
    rms_gate_kernel<<<BL, 256, 0, stream>>>(yssm, zx, norm_w, yg);
    // 6) out_proj
    dim3 g2(D_MODEL / GBN, BL / GBM);
    gemm_nt_f32<<<g2, 256, 0, stream>>>(yg, W_out, out, BL, D_MODEL, D_INNER,
                                        D_INNER, D_INNER, D_MODEL);
}

// Round 3
// 260.538 us; speedup vs baseline: 4.5797x; 2.7289x over previous
//
#include <hip/hip_runtime.h>
#include <hip/hip_bf16.h>
#include <math.h>

// Problem dims
#define D_MODEL   1024
#define D_INNER   2048
#define NHEADS    32
#define HEADDIM   64
#define D_STATE   64
#define CONV_DIM  2176            // D_INNER + 2*D_STATE
#define D_IN_PROJ 4256            // 2*D_INNER + 2*D_STATE + NHEADS
#define ZXLD      4352            // D_IN_PROJ padded to a multiple of 128
#define BATCH     2
#define SEQLEN    1024
#define BL        (BATCH * SEQLEN)
#define RMS_EPS   1.1920929e-07f

#define QCHUNK 64
#define NC     (SEQLEN / QCHUNK)

typedef __attribute__((ext_vector_type(8))) short short8;
typedef __attribute__((ext_vector_type(4))) float f32x4;
typedef __attribute__((ext_vector_type(8))) unsigned short ushort8v;

__device__ __forceinline__ unsigned short f2bf(float f) {
    unsigned u = __builtin_bit_cast(unsigned, f);
    unsigned r = u + 0x7FFFu + ((u >> 16) & 1u);   // RTNE
    return (unsigned short)(r >> 16);
}

__device__ __forceinline__ void gload_lds16(const void* g, void* l) {
    __builtin_amdgcn_global_load_lds(
        (const __attribute__((address_space(1))) void*)g,
        (__attribute__((address_space(3))) void*)l, 16, 0, 0);
}

// ---------------------------------------------------------------------------
// bf16 MFMA GEMM, NT: C[m,n] = sum_k A[m,k]*B[n,k].  A: MxK, B: NxK (row-major
// bf16 as ushort).  M%BM==0, N%BN==0, K%32==0.  4 waves = WR x WC grid.
// m97 structure: global_load_lds(16B) staging, 2 barriers / K-step.
// ---------------------------------------------------------------------------
template<int BM, int BN, int WR, int WC>
__global__ __launch_bounds__(256) void gemm_bf16_nt(
    const unsigned short* __restrict__ A, const unsigned short* __restrict__ B,
    float* __restrict__ C, int K, int ldc)
{
    constexpr int RM = BM / WR;     // rows per wave
    constexpr int RN = BN / WC;     // cols per wave
    constexpr int MF = RM / 16;     // m fragments
    constexpr int NF = RN / 16;     // n fragments
    constexpr int GA = BM / 64;     // 16-row staging groups per wave (A)
    constexpr int GB = BN / 64;     // (B)

    __shared__ unsigned short As[BM][32];
    __shared__ unsigned short Bs[BN][32];

    const int tid  = threadIdx.x;
    const int lane = tid & 63;
    const int w    = tid >> 6;
    const int wm   = w / WC;
    const int wn   = w % WC;
    const int m0   = blockIdx.y * BM;
    const int n0   = blockIdx.x * BN;

    const int lrow = lane >> 2;          // 0..15 within 16-row group
    const int lcol = (lane & 3) * 8;     // bf16 k-offset

    f32x4 acc[MF][NF];
#pragma unroll
    for (int mi = 0; mi < MF; ++mi)
#pragma unroll
        for (int ni = 0; ni < NF; ++ni) acc[mi][ni] = (f32x4){0.f, 0.f, 0.f, 0.f};

    for (int k0 = 0; k0 < K; k0 += 32) {
        __syncthreads();   // previous compute done before overwriting LDS
#pragma unroll
        for (int q = 0; q < GA; ++q) {
            const int g = w * GA + q;
            const unsigned short* gp = A + (size_t)(m0 + g * 16 + lrow) * K + k0 + lcol;
            gload_lds16(gp, &As[g * 16][0]);
        }
#pragma unroll
        for (int q = 0; q < GB; ++q) {
            const int g = w * GB + q;
            const unsigned short* gp = B + (size_t)(n0 + g * 16 + lrow) * K + k0 + lcol;
            gload_lds16(gp, &Bs[g * 16][0]);
        }
        __syncthreads();   // compiler drains vmcnt before barrier -> LDS valid

        short8 av[MF], bv[NF];
#pragma unroll
        for (int mi = 0; mi < MF; ++mi)
            av[mi] = *(const short8*)&As[wm * RM + mi * 16 + (lane & 15)][(lane >> 4) * 8];
#pragma unroll
        for (int ni = 0; ni < NF; ++ni)
            bv[ni] = *(const short8*)&Bs[wn * RN + ni * 16 + (lane & 15)][(lane >> 4) * 8];
#pragma unroll
        for (int mi = 0; mi < MF; ++mi)
#pragma unroll
            for (int ni = 0; ni < NF; ++ni)
                acc[mi][ni] = __builtin_amdgcn_mfma_f32_16x16x32_bf16(
                    av[mi], bv[ni], acc[mi][ni], 0, 0, 0);
    }

    // C/D layout: col = lane&15, row = (lane>>4)*4 + reg   [m89/m91 verified]
    const int crow = (lane >> 4) * 4;
    const int ccol = lane & 15;
#pragma unroll
    for (int mi = 0; mi < MF; ++mi)
#pragma unroll
        for (int ni = 0; ni < NF; ++ni) {
            const int row0 = m0 + wm * RM + mi * 16 + crow;
            const int col  = n0 + wn * RN + ni * 16 + ccol;
#pragma unroll
            for (int r = 0; r < 4; ++r)
                C[(size_t)(row0 + r) * ldc + col] = acc[mi][ni][r];
        }
}

// ---------------------------------------------------------------------------
// fp32 -> bf16 casts
// ---------------------------------------------------------------------------
__global__ __launch_bounds__(256) void cast_bf16_kernel(
    const float* __restrict__ src, unsigned short* __restrict__ dst, int n4)
{
    const int i = (blockIdx.x * 256 + threadIdx.x);
    if (i >= n4) return;
    float4 v = *(const float4*)(src + (size_t)i * 4);
    ushort4 o;
    o.x = f2bf(v.x); o.y = f2bf(v.y); o.z = f2bf(v.z); o.w = f2bf(v.w);
    *(ushort4*)(dst + (size_t)i * 4) = o;
}

// W_in cast with zero-padding from D_IN_PROJ to ZXLD rows (K=D_MODEL cols)
__global__ __launch_bounds__(256) void cast_win_pad_kernel(
    const float* __restrict__ src, unsigned short* __restrict__ dst)
{
    const int i = (blockIdx.x * 256 + threadIdx.x);   // over ZXLD*D_MODEL/4
    if (i >= ZXLD * D_MODEL / 4) return;
    const int e0 = i * 4;
    const int row = e0 >> 10;                          // D_MODEL = 1024
    ushort4 o = {0, 0, 0, 0};
    if (row < D_IN_PROJ) {
        float4 v = *(const float4*)(src + (size_t)e0);
        o.x = f2bf(v.x); o.y = f2bf(v.y); o.z = f2bf(v.z); o.w = f2bf(v.w);
    }
    *(ushort4*)(dst + (size_t)e0) = o;
}

// ---------------------------------------------------------------------------
// dt = softplus(dt_raw + dt_bias), transposed: dtt[b][h][l]
// ---------------------------------------------------------------------------
__global__ __launch_bounds__(256) void dt_softplus_kernel(
    const float* __restrict__ zx, const float* __restrict__ dt_bias,
    float* __restrict__ dtt)
{
    const int idx = blockIdx.x * 256 + threadIdx.x;   // BL*NHEADS
    const int m = idx >> 5;
    const int hd = idx & 31;
    const int b = m >> 10;
    const int l = m & (SEQLEN - 1);
    const float v = zx[(size_t)m * ZXLD + (D_INNER + CONV_DIM) + hd] + dt_bias[hd];
    const float sp = (v > 20.f) ? v : log1pf(expf(v));
    dtt[((size_t)b * NHEADS + hd) * SEQLEN + l] = sp;
}

// ---------------------------------------------------------------------------
// causal depthwise conv (D_CONV=4) + silu
// ---------------------------------------------------------------------------
__global__ __launch_bounds__(256) void conv_silu_kernel(
    const float* __restrict__ zx, const float* __restrict__ conv_w,
    const float* __restrict__ conv_b, float* __restrict__ xc)
{
    const int idx = blockIdx.x * 256 + threadIdx.x;   // BL*CONV_DIM
    const int m = idx / CONV_DIM;
    const int c = idx - m * CONV_DIM;
    const int l = m & (SEQLEN - 1);
    float acc = conv_b[c];
    const float* base = zx + (size_t)m * ZXLD + D_INNER + c;
#pragma unroll
    for (int k = 0; k < 4; ++k) {
        const int ll = l - 3 + k;
        if (ll >= 0)
            acc = fmaf(base[(ptrdiff_t)(k - 3) * ZXLD], conv_w[c * 4 + k], acc);
    }
    xc[idx] = acc / (1.f + expf(-acc));
}

// ---------------------------------------------------------------------------
// stage a 64x64 fp32 tile into padded LDS
// ---------------------------------------------------------------------------
__device__ inline void stage_tile64(const float* __restrict__ g, size_t gstride,
                                    float (*lds)[QCHUNK + 1], int tid)
{
    const int r = tid >> 2;
    const int q = (tid & 3) * 16;
    const float* src = g + (size_t)r * gstride + q;
    float* dst = &lds[r][q];
#pragma unroll
    for (int k = 0; k < 4; ++k) {
        float4 v = *(const float4*)(src + k * 4);
        dst[k * 4 + 0] = v.x; dst[k * 4 + 1] = v.y;
        dst[k * 4 + 2] = v.z; dst[k * 4 + 3] = v.w;
    }
}

// ---------------------------------------------------------------------------
// Phase A: S_intra[n,p] = sum_t exp(cum_end-cum_t)*dt_t*B[t,n]*x[t,p]
// ---------------------------------------------------------------------------
__global__ __launch_bounds__(256) void chunk_state_kernel(
    const float* __restrict__ xc, const float* __restrict__ dtt,
    const float* __restrict__ A_log,
    float* __restrict__ Sintra, float* __restrict__ cumA)
{
    const int bid = blockIdx.x;
    const int c = bid & (NC - 1);
    const int h = (bid >> 4) & (NHEADS - 1);
    const int b = bid >> 9;
    const int tid = threadIdx.x;

    __shared__ float sX[QCHUNK][QCHUNK + 1];
    __shared__ float sB[QCHUNK][QCHUNK + 1];
    __shared__ float sw[QCHUNK];

    const float* rbase = xc + ((size_t)b * SEQLEN + c * QCHUNK) * CONV_DIM;
    stage_tile64(rbase + h * HEADDIM, CONV_DIM, sX, tid);
    stage_tile64(rbase + D_INNER, CONV_DIM, sB, tid);

    if (tid < QCHUNK) {
        const float A = -expf(A_log[h]);
        const float dtv = dtt[((size_t)b * NHEADS + h) * SEQLEN + c * QCHUNK + tid];
        float cum = dtv * A;
#pragma unroll
        for (int off = 1; off < 64; off <<= 1) {
            const float o = __shfl_up(cum, off, 64);
            if (tid >= off) cum += o;
        }
        const float cum_end = __shfl(cum, 63, 64);
        sw[tid] = expf(cum_end - cum) * dtv;
        cumA[(size_t)bid * QCHUNK + tid] = cum;
    }
    __syncthreads();

    const int p = tid & 63;
    const int nq = tid >> 6;
    float acc[16];
#pragma unroll
    for (int j = 0; j < 16; ++j) acc[j] = 0.f;

    for (int t = 0; t < QCHUNK; ++t) {
        const float wx = sw[t] * sX[t][p];
#pragma unroll
        for (int j = 0; j < 16; ++j)
            acc[j] = fmaf(wx, sB[t][nq * 16 + j], acc[j]);
    }

    float* sout = Sintra + (size_t)bid * (D_STATE * HEADDIM);
#pragma unroll
    for (int j = 0; j < 16; ++j)
        sout[(nq * 16 + j) * HEADDIM + p] = acc[j];
}

// ---------------------------------------------------------------------------
// Phase B: inter-chunk recurrence, in-place (SP[c] <- state before chunk c)
// ---------------------------------------------------------------------------
__global__ __launch_bounds__(256) void state_pass_kernel(
    float* __restrict__ S, const float* __restrict__ cumA)
{
    const int bh = blockIdx.x;
    const int tid = threadIdx.x;
    const int e0 = tid * 16;

    float run[16];
#pragma unroll
    for (int j = 0; j < 16; ++j) run[j] = 0.f;

    for (int c = 0; c < NC; ++c) {
        const size_t blk = (size_t)(bh * NC + c);
        const float g = expf(cumA[blk * QCHUNK + (QCHUNK - 1)]);
        float* p = S + blk * (D_STATE * HEADDIM) + e0;
        float s[16];
#pragma unroll
        for (int k = 0; k < 4; ++k) {
            float4 v = *(const float4*)(p + k * 4);
            s[k * 4 + 0] = v.x; s[k * 4 + 1] = v.y; s[k * 4 + 2] = v.z; s[k * 4 + 3] = v.w;
        }
#pragma unroll
        for (int k = 0; k < 4; ++k)
            *(float4*)(p + k * 4) = make_float4(run[k * 4 + 0], run[k * 4 + 1],
                                                run[k * 4 + 2], run[k * 4 + 3]);
#pragma unroll
        for (int j = 0; j < 16; ++j)
            run[j] = fmaf(g, run[j], s[j]);
    }
}

// ---------------------------------------------------------------------------
// Phase C: per-chunk output
// ---------------------------------------------------------------------------
__global__ __launch_bounds__(256) void chunk_output_kernel(
    const float* __restrict__ xc, const float* __restrict__ dtt,
    const float* __restrict__ SP, const float* __restrict__ cumA,
    const float* __restrict__ D_param, float* __restrict__ y)
{
    const int bid = blockIdx.x;
    const int c = bid & (NC - 1);
    const int h = (bid >> 4) & (NHEADS - 1);
    const int b = bid >> 9;
    const int tid = threadIdx.x;

    __shared__ float sBSP[QCHUNK][QCHUNK + 1];
    __shared__ float sC[QCHUNK][QCHUNK + 1];
    __shared__ float sX[QCHUNK][QCHUNK + 1];
    __shared__ float sM[QCHUNK][QCHUNK + 1];
    __shared__ float scum[QCHUNK];
    __shared__ float sdt[QCHUNK];

    const float* rbase = xc + ((size_t)b * SEQLEN + c * QCHUNK) * CONV_DIM;
    stage_tile64(rbase + h * HEADDIM, CONV_DIM, sX, tid);
    stage_tile64(rbase + D_INNER, CONV_DIM, sBSP, tid);
    stage_tile64(rbase + D_INNER + D_STATE, CONV_DIM, sC, tid);
    if (tid < QCHUNK) {
        scum[tid] = cumA[(size_t)bid * QCHUNK + tid];
        sdt[tid] = dtt[((size_t)b * NHEADS + h) * SEQLEN + c * QCHUNK + tid];
    }
    __syncthreads();

    {
        const int s = tid & 63;
        const int tq = tid >> 6;
#pragma unroll
        for (int i = 0; i < 16; ++i) {
            const int t = tq * 16 + i;
            float dot = 0.f;
#pragma unroll 8
            for (int n = 0; n < QCHUNK; ++n)
                dot = fmaf(sC[t][n], sBSP[s][n], dot);
            float wv = 0.f;
            if (s <= t) wv = dot * expf(scum[t] - scum[s]) * sdt[s];
            sM[t][s] = wv;
        }
    }
    __syncthreads();

    stage_tile64(SP + (size_t)bid * (D_STATE * HEADDIM), HEADDIM, sBSP, tid);
    __syncthreads();

    const float Dp = D_param[h];
    const int p = tid & 63;
    const int tq = tid >> 6;
    float* ybase = y + (((size_t)b * SEQLEN + c * QCHUNK) * D_INNER) + h * HEADDIM + p;
#pragma unroll
    for (int i = 0; i < 16; ++i) {
        const int t = tq * 16 + i;
        float a_in = 0.f;
#pragma unroll 8
        for (int s = 0; s < QCHUNK; ++s)
            a_in = fmaf(sM[t][s], sX[s][p], a_in);
        float a_st = 0.f;
#pragma unroll 8
        for (int n = 0; n < QCHUNK; ++n)
            a_st = fmaf(sC[t][n], sBSP[n][p], a_st);
        ybase[(size_t)t * D_INNER] = a_in + expf(scum[t]) * a_st + Dp * sX[t][p];
    }
}

// ---------------------------------------------------------------------------
// RMSNorm * norm_w * silu(z)  -> bf16 output (feeds out-proj MFMA GEMM)
// ---------------------------------------------------------------------------
__global__ __launch_bounds__(256) void rms_gate_kernel(
    const float* __restrict__ y, const float* __restrict__ zx,
    const float* __restrict__ norm_w, unsigned short* __restrict__ out)
{
    const int m = blockIdx.x;
    const int tid = threadIdx.x;
    const float* yr = y + (size_t)m * D_INNER;
    const float* zr = zx + (size_t)m * ZXLD;

    float4 v0 = *(const float4*)(yr + tid * 8);
    float4 v1 = *(const float4*)(yr + tid * 8 + 4);
    float yv[8] = {v0.x, v0.y, v0.z, v0.w, v1.x, v1.y, v1.z, v1.w};
    float ss = 0.f;
#pragma unroll
    for (int j = 0; j < 8; ++j) ss += yv[j] * yv[j];
#pragma unroll
    for (int off = 32; off > 0; off >>= 1) ss += __shfl_xor(ss, off, 64);
    __shared__ float sred[4];
    if ((tid & 63) == 0) sred[tid >> 6] = ss;
    __syncthreads();
    const float tot = sred[0] + sred[1] + sred[2] + sred[3];
    const float inv = rsqrtf(tot * (1.f / D_INNER) + RMS_EPS);

    float4 z0 = *(const float4*)(zr + tid * 8);
    float4 z1 = *(const float4*)(zr + tid * 8 + 4);
    float zv[8] = {z0.x, z0.y, z0.z, z0.w, z1.x, z1.y, z1.z, z1.w};
    const float* nw = norm_w + tid * 8;
    ushort8v o;
#pragma unroll
    for (int j = 0; j < 8; ++j) {
        const float zz = zv[j];
        const float sig = 1.f / (1.f + expf(-zz));
        o[j] = f2bf(yv[j] * inv * nw[j] * (zz * sig));
    }
    *(ushort8v*)(out + (size_t)m * D_INNER + tid * 8) = o;
}

// ---------------------------------------------------------------------------
// Workspace layout (float-equivalents), ~91.8 MB total:
//   zx    : 2048*4352            = 8,912,896 f
//   xc    : BL*CONV_DIM          = 4,456,448 f   (later reused: ygb bf16)
//   dtt   : 65,536 f
//   cumA  : 65,536 f
//   S     : 4,194,304 f          (first staged as W_in bf16 [alias], then S)
//   yssm  : 4,194,304 f          (first staged as x bf16 [alias], then yssm)
//   wob   : 1,048,576 f          (W_out bf16)
// Alias safety: winb read only by gemm1 which completes before chunk_state
// writes S; xb read only by gemm1 before chunk_output writes yssm; ygb
// written by rms_gate after the last read of xc (chunk_output).
// ---------------------------------------------------------------------------
extern "C" void kernel_launch(void* const* d_in, const int* in_sizes, int n_in,
                              void* d_out, int out_size, void* d_ws, size_t ws_size,
                              hipStream_t stream)
{
    const float* x       = (const float*)d_in[0];
    const float* W_in    = (const float*)d_in[1];
    const float* conv_w  = (const float*)d_in[2];
    const float* conv_b  = (const float*)d_in[3];
    const float* dt_bias = (const float*)d_in[4];
    const float* A_log   = (const float*)d_in[5];
    const float* D_param = (const float*)d_in[6];
    const float* norm_w  = (const float*)d_in[7];
    const float* W_out   = (const float*)d_in[8];
    float* out = (float*)d_out;

    float* ws   = (float*)d_ws;
    float* zx   = ws;
    float* xc   = zx + (size_t)BL * ZXLD;
    float* dtt  = xc + (size_t)BL * CONV_DIM;
    float* cumA = dtt + (size_t)BATCH * NHEADS * SEQLEN;
    float* S    = cumA + (size_t)BATCH * NHEADS * NC * QCHUNK;
    float* yssm = S + (size_t)BATCH * NHEADS * NC * D_STATE * HEADDIM;
    float* wob  = yssm + (size_t)BL * D_INNER;

    unsigned short* winb  = (unsigned short*)S;     // W_in bf16 (padded rows)
    unsigned short* xb    = (unsigned short*)yssm;  // x bf16
    unsigned short* woutb = (unsigned short*)wob;   // W_out bf16
    unsigned short* ygb   = (unsigned short*)xc;    // gated y bf16

    // 0) casts
    cast_bf16_kernel<<<(BL * D_MODEL / 4 + 255) / 256, 256, 0, stream>>>(
        x, xb, BL * D_MODEL / 4);
    cast_win_pad_kernel<<<(ZXLD * D_MODEL / 4 + 255) / 256, 256, 0, stream>>>(W_in, winb);
    cast_bf16_kernel<<<(D_MODEL * D_INNER / 4 + 255) / 256, 256, 0, stream>>>(
        W_out, woutb, D_MODEL * D_INNER / 4);

    // 1) in_proj (bf16 MFMA): zx[m,n] = sum_k xb[m,k]*winb[n,k]
    gemm_bf16_nt<128, 128, 2, 2><<<dim3(ZXLD / 128, BL / 128), 256, 0, stream>>>(
        xb, winb, zx, D_MODEL, ZXLD);

    // 2) dt softplus (transposed)
    dt_softplus_kernel<<<(BL * NHEADS) / 256, 256, 0, stream>>>(zx, dt_bias, dtt);
    // 3) conv1d + silu
    conv_silu_kernel<<<(BL * CONV_DIM) / 256, 256, 0, stream>>>(zx, conv_w, conv_b, xc);
    // 4) chunked SSM scan
    chunk_state_kernel<<<BATCH * NHEADS * NC, 256, 0, stream>>>(xc, dtt, A_log, S, cumA);
    state_pass_kernel<<<BATCH * NHEADS, 256, 0, stream>>>(S, cumA);
    chunk_output_kernel<<<BATCH * NHEADS * NC, 256, 0, stream>>>(xc, dtt, S, cumA,
                                                                 D_param, yssm);
    // 5) RMSNorm + gate -> bf16
    rms_gate_kernel<<<BL, 256, 0, stream>>>(yssm, zx, norm_w, ygb);

    // 6) out_proj (bf16 MFMA): out[m,d] = sum_j ygb[m,j]*woutb[d,j]
    gemm_bf16_nt<64, 128, 1, 4><<<dim3(D_MODEL / 128, BL / 64), 256, 0, stream>>>(
        ygb, woutb, out, D_INNER, D_MODEL);
}

// Round 4
// 169.249 us; speedup vs baseline: 7.0499x; 1.5394x over previous
//
#include <hip/hip_runtime.h>
#include <hip/hip_bf16.h>
#include <math.h>

// Problem dims
#define D_MODEL   1024
#define D_INNER   2048
#define NHEADS    32
#define HEADDIM   64
#define D_STATE   64
#define CONV_DIM  2176            // D_INNER + 2*D_STATE
#define D_IN_PROJ 4256            // 2*D_INNER + 2*D_STATE + NHEADS
#define ZXLD      4352            // padded to 128
#define BATCH     2
#define SEQLEN    1024
#define BL        (BATCH * SEQLEN)
#define RMS_EPS   1.1920929e-07f

#define QCHUNK 64
#define NC     (SEQLEN / QCHUNK)

typedef __attribute__((ext_vector_type(8))) short short8;
typedef __attribute__((ext_vector_type(4))) float f32x4;
typedef __attribute__((ext_vector_type(8))) unsigned short ushort8v;

__device__ __forceinline__ unsigned short f2bf(float f) {
    unsigned u = __builtin_bit_cast(unsigned, f);
    unsigned r = u + 0x7FFFu + ((u >> 16) & 1u);   // RTNE
    return (unsigned short)(r >> 16);
}
__device__ __forceinline__ float bf2f(unsigned short u) {
    unsigned v = ((unsigned)u) << 16;
    return __builtin_bit_cast(float, v);
}
__device__ __forceinline__ void gload_lds16(const void* g, void* l) {
    __builtin_amdgcn_global_load_lds(
        (const __attribute__((address_space(1))) void*)g,
        (__attribute__((address_space(3))) void*)l, 16, 0, 0);
}

// ---------------------------------------------------------------------------
// bf16 MFMA GEMM, NT: C[m,n] = sum_k A[m,k]*B[n,k]  (m97 structure)
// ---------------------------------------------------------------------------
template<int BM, int BN, int WR, int WC>
__global__ __launch_bounds__(256) void gemm_bf16_nt(
    const unsigned short* __restrict__ A, const unsigned short* __restrict__ B,
    float* __restrict__ C, int K, int ldc)
{
    constexpr int RM = BM / WR;
    constexpr int RN = BN / WC;
    constexpr int MF = RM / 16;
    constexpr int NF = RN / 16;
    constexpr int GA = BM / 64;
    constexpr int GB = BN / 64;

    __shared__ unsigned short As[BM][32];
    __shared__ unsigned short Bs[BN][32];

    const int tid  = threadIdx.x;
    const int lane = tid & 63;
    const int w    = tid >> 6;
    const int wm   = w / WC;
    const int wn   = w % WC;
    const int m0   = blockIdx.y * BM;
    const int n0   = blockIdx.x * BN;

    const int lrow = lane >> 2;
    const int lcol = (lane & 3) * 8;

    f32x4 acc[MF][NF];
#pragma unroll
    for (int mi = 0; mi < MF; ++mi)
#pragma unroll
        for (int ni = 0; ni < NF; ++ni) acc[mi][ni] = (f32x4){0.f, 0.f, 0.f, 0.f};

    for (int k0 = 0; k0 < K; k0 += 32) {
        __syncthreads();
#pragma unroll
        for (int q = 0; q < GA; ++q) {
            const int g = w * GA + q;
            const unsigned short* gp = A + (size_t)(m0 + g * 16 + lrow) * K + k0 + lcol;
            gload_lds16(gp, &As[g * 16][0]);
        }
#pragma unroll
        for (int q = 0; q < GB; ++q) {
            const int g = w * GB + q;
            const unsigned short* gp = B + (size_t)(n0 + g * 16 + lrow) * K + k0 + lcol;
            gload_lds16(gp, &Bs[g * 16][0]);
        }
        __syncthreads();

        short8 av[MF], bv[NF];
#pragma unroll
        for (int mi = 0; mi < MF; ++mi)
            av[mi] = *(const short8*)&As[wm * RM + mi * 16 + (lane & 15)][(lane >> 4) * 8];
#pragma unroll
        for (int ni = 0; ni < NF; ++ni)
            bv[ni] = *(const short8*)&Bs[wn * RN + ni * 16 + (lane & 15)][(lane >> 4) * 8];
#pragma unroll
        for (int mi = 0; mi < MF; ++mi)
#pragma unroll
            for (int ni = 0; ni < NF; ++ni)
                acc[mi][ni] = __builtin_amdgcn_mfma_f32_16x16x32_bf16(
                    av[mi], bv[ni], acc[mi][ni], 0, 0, 0);
    }

    const int crow = (lane >> 4) * 4;
    const int ccol = lane & 15;
#pragma unroll
    for (int mi = 0; mi < MF; ++mi)
#pragma unroll
        for (int ni = 0; ni < NF; ++ni) {
            const int row0 = m0 + wm * RM + mi * 16 + crow;
            const int col  = n0 + wn * RN + ni * 16 + ccol;
#pragma unroll
            for (int r = 0; r < 4; ++r)
                C[(size_t)(row0 + r) * ldc + col] = acc[mi][ni][r];
        }
}

// ---------------------------------------------------------------------------
// fp32 -> bf16 casts
// ---------------------------------------------------------------------------
__global__ __launch_bounds__(256) void cast_bf16_kernel(
    const float* __restrict__ src, unsigned short* __restrict__ dst, int n4)
{
    const int i = (blockIdx.x * 256 + threadIdx.x);
    if (i >= n4) return;
    float4 v = *(const float4*)(src + (size_t)i * 4);
    ushort4 o;
    o.x = f2bf(v.x); o.y = f2bf(v.y); o.z = f2bf(v.z); o.w = f2bf(v.w);
    *(ushort4*)(dst + (size_t)i * 4) = o;
}

__global__ __launch_bounds__(256) void cast_win_pad_kernel(
    const float* __restrict__ src, unsigned short* __restrict__ dst)
{
    const int i = (blockIdx.x * 256 + threadIdx.x);
    if (i >= ZXLD * D_MODEL / 4) return;
    const int e0 = i * 4;
    const int row = e0 >> 10;
    ushort4 o = {0, 0, 0, 0};
    if (row < D_IN_PROJ) {
        float4 v = *(const float4*)(src + (size_t)e0);
        o.x = f2bf(v.x); o.y = f2bf(v.y); o.z = f2bf(v.z); o.w = f2bf(v.w);
    }
    *(ushort4*)(dst + (size_t)e0) = o;
}

// ---------------------------------------------------------------------------
// dt = softplus(dt_raw + dt_bias), transposed: dtt[b][h][l]
// ---------------------------------------------------------------------------
__global__ __launch_bounds__(256) void dt_softplus_kernel(
    const float* __restrict__ zx, const float* __restrict__ dt_bias,
    float* __restrict__ dtt)
{
    const int idx = blockIdx.x * 256 + threadIdx.x;
    const int m = idx >> 5;
    const int hd = idx & 31;
    const int b = m >> 10;
    const int l = m & (SEQLEN - 1);
    const float v = zx[(size_t)m * ZXLD + (D_INNER + CONV_DIM) + hd] + dt_bias[hd];
    const float sp = (v > 20.f) ? v : log1pf(expf(v));
    dtt[((size_t)b * NHEADS + hd) * SEQLEN + l] = sp;
}

// ---------------------------------------------------------------------------
// causal depthwise conv (D_CONV=4) + silu
// ---------------------------------------------------------------------------
__global__ __launch_bounds__(256) void conv_silu_kernel(
    const float* __restrict__ zx, const float* __restrict__ conv_w,
    const float* __restrict__ conv_b, float* __restrict__ xc)
{
    const int idx = blockIdx.x * 256 + threadIdx.x;
    const int m = idx / CONV_DIM;
    const int c = idx - m * CONV_DIM;
    const int l = m & (SEQLEN - 1);
    float acc = conv_b[c];
    const float* base = zx + (size_t)m * ZXLD + D_INNER + c;
#pragma unroll
    for (int k = 0; k < 4; ++k) {
        const int ll = l - 3 + k;
        if (ll >= 0)
            acc = fmaf(base[(ptrdiff_t)(k - 3) * ZXLD], conv_w[c * 4 + k], acc);
    }
    xc[idx] = acc / (1.f + expf(-acc));
}

// ---------------------------------------------------------------------------
// LDS staging helpers: 64x64 fp32 global tile -> bf16 LDS tile [64][72]
// normal:      lds[r][c] = src[r*stride + c]
// transposed:  lds[c][r] = src[r*stride + c] * scale
// ---------------------------------------------------------------------------
__device__ __forceinline__ void stage_bf16_tile(
    const float* __restrict__ src, size_t stride,
    unsigned short (*lds)[72], int tid)
{
    const int r = tid >> 2, q = (tid & 3) * 16;
    const float* s = src + (size_t)r * stride + q;
#pragma unroll
    for (int k = 0; k < 4; ++k) {
        float4 v = *(const float4*)(s + k * 4);
        ushort4 o = {f2bf(v.x), f2bf(v.y), f2bf(v.z), f2bf(v.w)};
        *(ushort4*)&lds[r][q + k * 4] = o;
    }
}

__device__ __forceinline__ void stage_bf16_tile_T(
    const float* __restrict__ src, size_t stride,
    unsigned short (*lds)[72], int tid, float scale)
{
    const int r = tid >> 2, q = (tid & 3) * 16;
    const float* s = src + (size_t)r * stride + q;
#pragma unroll
    for (int k = 0; k < 16; k += 4) {
        float4 v = *(const float4*)(s + k);
        lds[q + k + 0][r] = f2bf(v.x * scale);
        lds[q + k + 1][r] = f2bf(v.y * scale);
        lds[q + k + 2][r] = f2bf(v.z * scale);
        lds[q + k + 3][r] = f2bf(v.w * scale);
    }
}

#define MFMA_BF16 __builtin_amdgcn_mfma_f32_16x16x32_bf16

// ---------------------------------------------------------------------------
// Phase A (MFMA): S[n,p] = sum_t (w_t*B[t,n]) * X[t,p],  w_t = exp(cum_end-cum_t)*dt_t
// A-op = sBT[n][t] (weighted, transposed), B-op = sXT[p][t].
// ---------------------------------------------------------------------------
__global__ __launch_bounds__(256) void chunk_state_kernel(
    const float* __restrict__ xc, const float* __restrict__ dtt,
    const float* __restrict__ A_log,
    float* __restrict__ Sintra, float* __restrict__ cumA)
{
    const int bid = blockIdx.x;
    const int c = bid & (NC - 1);
    const int h = (bid >> 4) & (NHEADS - 1);
    const int b = bid >> 9;
    const int tid = threadIdx.x;
    const int lane = tid & 63;
    const int w = tid >> 6;

    __shared__ unsigned short sXT[64][72];
    __shared__ unsigned short sBT[64][72];
    __shared__ float sw[64];

    const float* rbase = xc + ((size_t)b * SEQLEN + c * QCHUNK) * CONV_DIM;
    stage_bf16_tile_T(rbase + h * HEADDIM, CONV_DIM, sXT, tid, 1.f);

    if (tid < QCHUNK) {
        const float A = -expf(A_log[h]);
        const float dtv = dtt[((size_t)b * NHEADS + h) * SEQLEN + c * QCHUNK + tid];
        float cum = dtv * A;
#pragma unroll
        for (int off = 1; off < 64; off <<= 1) {
            const float o = __shfl_up(cum, off, 64);
            if (tid >= off) cum += o;
        }
        const float cum_end = __shfl(cum, 63, 64);
        sw[tid] = expf(cum_end - cum) * dtv;
        cumA[(size_t)bid * QCHUNK + tid] = cum;
    }
    __syncthreads();    // sw ready for weighted B staging

    {
        const int r = tid >> 2;
        stage_bf16_tile_T(rbase + D_INNER, CONV_DIM, sBT, tid, sw[r]);
    }
    __syncthreads();

    const int fr = lane & 15;
    const int ko = (lane >> 4) * 8;
    short8 a0 = *(const short8*)&sBT[w * 16 + fr][ko];
    short8 a1 = *(const short8*)&sBT[w * 16 + fr][ko + 32];

    float* sout = Sintra + (size_t)bid * (D_STATE * HEADDIM);
    const int nrow = w * 16 + (lane >> 4) * 4;
#pragma unroll
    for (int j = 0; j < 4; ++j) {
        short8 b0 = *(const short8*)&sXT[j * 16 + fr][ko];
        short8 b1 = *(const short8*)&sXT[j * 16 + fr][ko + 32];
        f32x4 a = (f32x4){0.f, 0.f, 0.f, 0.f};
        a = MFMA_BF16(a0, b0, a, 0, 0, 0);
        a = MFMA_BF16(a1, b1, a, 0, 0, 0);
        const int p = j * 16 + fr;
#pragma unroll
        for (int r = 0; r < 4; ++r)
            sout[(size_t)(nrow + r) * HEADDIM + p] = a[r];
    }
}

// ---------------------------------------------------------------------------
// Phase B: inter-chunk recurrence, in-place (unchanged, fp32)
// ---------------------------------------------------------------------------
__global__ __launch_bounds__(256) void state_pass_kernel(
    float* __restrict__ S, const float* __restrict__ cumA)
{
    const int bh = blockIdx.x;
    const int tid = threadIdx.x;
    const int e0 = tid * 16;

    float run[16];
#pragma unroll
    for (int j = 0; j < 16; ++j) run[j] = 0.f;

    for (int c = 0; c < NC; ++c) {
        const size_t blk = (size_t)(bh * NC + c);
        const float g = expf(cumA[blk * QCHUNK + (QCHUNK - 1)]);
        float* p = S + blk * (D_STATE * HEADDIM) + e0;
        float s[16];
#pragma unroll
        for (int k = 0; k < 4; ++k) {
            float4 v = *(const float4*)(p + k * 4);
            s[k * 4 + 0] = v.x; s[k * 4 + 1] = v.y; s[k * 4 + 2] = v.z; s[k * 4 + 3] = v.w;
        }
#pragma unroll
        for (int k = 0; k < 4; ++k)
            *(float4*)(p + k * 4) = make_float4(run[k * 4 + 0], run[k * 4 + 1],
                                                run[k * 4 + 2], run[k * 4 + 3]);
#pragma unroll
        for (int j = 0; j < 16; ++j)
            run[j] = fmaf(g, run[j], s[j]);
    }
}

// ---------------------------------------------------------------------------
// Phase C (MFMA): G = C.B^T; M = mask(G)*exp(dcum)*dt; Y = M.X + exp(cum)*C.SP + D*x
// ---------------------------------------------------------------------------
__global__ __launch_bounds__(256) void chunk_output_kernel(
    const float* __restrict__ xc, const float* __restrict__ dtt,
    const float* __restrict__ SP, const float* __restrict__ cumA,
    const float* __restrict__ D_param, float* __restrict__ y)
{
    const int bid = blockIdx.x;
    const int c = bid & (NC - 1);
    const int h = (bid >> 4) & (NHEADS - 1);
    const int b = bid >> 9;
    const int tid = threadIdx.x;
    const int lane = tid & 63;
    const int w = tid >> 6;

    __shared__ unsigned short sC[64][72];
    __shared__ unsigned short sB[64][72];
    __shared__ unsigned short sXT[64][72];
    __shared__ unsigned short sSPT[64][72];
    __shared__ unsigned short sM[64][72];
    __shared__ float scum[64], sdt[64];

    const float* rbase = xc + ((size_t)b * SEQLEN + c * QCHUNK) * CONV_DIM;
    stage_bf16_tile(rbase + D_INNER + D_STATE, CONV_DIM, sC, tid);
    stage_bf16_tile(rbase + D_INNER, CONV_DIM, sB, tid);
    stage_bf16_tile_T(rbase + h * HEADDIM, CONV_DIM, sXT, tid, 1.f);
    stage_bf16_tile_T(SP + (size_t)bid * (D_STATE * HEADDIM), HEADDIM, sSPT, tid, 1.f);
    if (tid < QCHUNK) {
        scum[tid] = cumA[(size_t)bid * QCHUNK + tid];
        sdt[tid] = dtt[((size_t)b * NHEADS + h) * SEQLEN + c * QCHUNK + tid];
    }
    __syncthreads();

    const int fr = lane & 15;
    const int ko = (lane >> 4) * 8;
    const int trow = w * 16 + (lane >> 4) * 4;

    short8 aC0 = *(const short8*)&sC[w * 16 + fr][ko];
    short8 aC1 = *(const short8*)&sC[w * 16 + fr][ko + 32];

    // --- G = C.B^T ---
    f32x4 g[4];
#pragma unroll
    for (int j = 0; j < 4; ++j) {
        short8 b0 = *(const short8*)&sB[j * 16 + fr][ko];
        short8 b1 = *(const short8*)&sB[j * 16 + fr][ko + 32];
        f32x4 a = (f32x4){0.f, 0.f, 0.f, 0.f};
        a = MFMA_BF16(aC0, b0, a, 0, 0, 0);
        a = MFMA_BF16(aC1, b1, a, 0, 0, 0);
        g[j] = a;
    }

    // --- decay mask -> sM (bf16) ---
    float ct[4];
#pragma unroll
    for (int r = 0; r < 4; ++r) ct[r] = scum[trow + r];
#pragma unroll
    for (int j = 0; j < 4; ++j) {
        const int s = j * 16 + fr;
        const float cs = scum[s], ds = sdt[s];
#pragma unroll
        for (int r = 0; r < 4; ++r) {
            const int t = trow + r;
            const float m = (s <= t) ? g[j][r] * expf(ct[r] - cs) * ds : 0.f;
            sM[t][s] = f2bf(m);
        }
    }
    __syncthreads();

    // --- Y1 = M.X, Y2 = C.SP ---
    short8 aM0 = *(const short8*)&sM[w * 16 + fr][ko];
    short8 aM1 = *(const short8*)&sM[w * 16 + fr][ko + 32];
    f32x4 y1[4], y2[4];
#pragma unroll
    for (int j = 0; j < 4; ++j) {
        short8 bx0 = *(const short8*)&sXT[j * 16 + fr][ko];
        short8 bx1 = *(const short8*)&sXT[j * 16 + fr][ko + 32];
        f32x4 a = (f32x4){0.f, 0.f, 0.f, 0.f};
        a = MFMA_BF16(aM0, bx0, a, 0, 0, 0);
        a = MFMA_BF16(aM1, bx1, a, 0, 0, 0);
        y1[j] = a;
        short8 bs0 = *(const short8*)&sSPT[j * 16 + fr][ko];
        short8 bs1 = *(const short8*)&sSPT[j * 16 + fr][ko + 32];
        f32x4 a2 = (f32x4){0.f, 0.f, 0.f, 0.f};
        a2 = MFMA_BF16(aC0, bs0, a2, 0, 0, 0);
        a2 = MFMA_BF16(aC1, bs1, a2, 0, 0, 0);
        y2[j] = a2;
    }

    const float Dp = D_param[h];
    float et[4];
#pragma unroll
    for (int r = 0; r < 4; ++r) et[r] = expf(ct[r]);
    float* ybase = y + (((size_t)b * SEQLEN + c * QCHUNK) * D_INNER) + h * HEADDIM;
#pragma unroll
    for (int j = 0; j < 4; ++j) {
        const int p = j * 16 + fr;
#pragma unroll
        for (int r = 0; r < 4; ++r) {
            const int t = trow + r;
            const float xv = bf2f(sXT[p][t]);
            ybase[(size_t)t * D_INNER + p] = y1[j][r] + et[r] * y2[j][r] + Dp * xv;
        }
    }
}

// ---------------------------------------------------------------------------
// RMSNorm * norm_w * silu(z) -> bf16
// ---------------------------------------------------------------------------
__global__ __launch_bounds__(256) void rms_gate_kernel(
    const float* __restrict__ y, const float* __restrict__ zx,
    const float* __restrict__ norm_w, unsigned short* __restrict__ out)
{
    const int m = blockIdx.x;
    const int tid = threadIdx.x;
    const float* yr = y + (size_t)m * D_INNER;
    const float* zr = zx + (size_t)m * ZXLD;

    float4 v0 = *(const float4*)(yr + tid * 8);
    float4 v1 = *(const float4*)(yr + tid * 8 + 4);
    float yv[8] = {v0.x, v0.y, v0.z, v0.w, v1.x, v1.y, v1.z, v1.w};
    float ss = 0.f;
#pragma unroll
    for (int j = 0; j < 8; ++j) ss += yv[j] * yv[j];
#pragma unroll
    for (int off = 32; off > 0; off >>= 1) ss += __shfl_xor(ss, off, 64);
    __shared__ float sred[4];
    if ((tid & 63) == 0) sred[tid >> 6] = ss;
    __syncthreads();
    const float tot = sred[0] + sred[1] + sred[2] + sred[3];
    const float inv = rsqrtf(tot * (1.f / D_INNER) + RMS_EPS);

    float4 z0 = *(const float4*)(zr + tid * 8);
    float4 z1 = *(const float4*)(zr + tid * 8 + 4);
    float zv[8] = {z0.x, z0.y, z0.z, z0.w, z1.x, z1.y, z1.z, z1.w};
    const float* nw = norm_w + tid * 8;
    ushort8v o;
#pragma unroll
    for (int j = 0; j < 8; ++j) {
        const float zz = zv[j];
        const float sig = 1.f / (1.f + expf(-zz));
        o[j] = f2bf(yv[j] * inv * nw[j] * (zz * sig));
    }
    *(ushort8v*)(out + (size_t)m * D_INNER + tid * 8) = o;
}

// ---------------------------------------------------------------------------
// Workspace (float-equivalents):
//   zx, xc, dtt, cumA, S, yssm, wob  (aliases: winb=S, xb=yssm, woutb=wob,
//   ygb=xc) -- alias safety documented in R3; ordering unchanged.
// ---------------------------------------------------------------------------
extern "C" void kernel_launch(void* const* d_in, const int* in_sizes, int n_in,
                              void* d_out, int out_size, void* d_ws, size_t ws_size,
                              hipStream_t stream)
{
    const float* x       = (const float*)d_in[0];
    const float* W_in    = (const float*)d_in[1];
    const float* conv_w  = (const float*)d_in[2];
    const float* conv_b  = (const float*)d_in[3];
    const float* dt_bias = (const float*)d_in[4];
    const float* A_log   = (const float*)d_in[5];
    const float* D_param = (const float*)d_in[6];
    const float* norm_w  = (const float*)d_in[7];
    const float* W_out   = (const float*)d_in[8];
    float* out = (float*)d_out;

    float* ws   = (float*)d_ws;
    float* zx   = ws;
    float* xc   = zx + (size_t)BL * ZXLD;
    float* dtt  = xc + (size_t)BL * CONV_DIM;
    float* cumA = dtt + (size_t)BATCH * NHEADS * SEQLEN;
    float* S    = cumA + (size_t)BATCH * NHEADS * NC * QCHUNK;
    float* yssm = S + (size_t)BATCH * NHEADS * NC * D_STATE * HEADDIM;
    float* wob  = yssm + (size_t)BL * D_INNER;

    unsigned short* winb  = (unsigned short*)S;
    unsigned short* xb    = (unsigned short*)yssm;
    unsigned short* woutb = (unsigned short*)wob;
    unsigned short* ygb   = (unsigned short*)xc;

    // 0) casts
    cast_bf16_kernel<<<(BL * D_MODEL / 4 + 255) / 256, 256, 0, stream>>>(
        x, xb, BL * D_MODEL / 4);
    cast_win_pad_kernel<<<(ZXLD * D_MODEL / 4 + 255) / 256, 256, 0, stream>>>(W_in, winb);
    cast_bf16_kernel<<<(D_MODEL * D_INNER / 4 + 255) / 256, 256, 0, stream>>>(
        W_out, woutb, D_MODEL * D_INNER / 4);

    // 1) in_proj (bf16 MFMA)
    gemm_bf16_nt<128, 128, 2, 2><<<dim3(ZXLD / 128, BL / 128), 256, 0, stream>>>(
        xb, winb, zx, D_MODEL, ZXLD);

    // 2) dt softplus
    dt_softplus_kernel<<<(BL * NHEADS) / 256, 256, 0, stream>>>(zx, dt_bias, dtt);
    // 3) conv1d + silu
    conv_silu_kernel<<<(BL * CONV_DIM) / 256, 256, 0, stream>>>(zx, conv_w, conv_b, xc);
    // 4) chunked SSM scan (MFMA phases A & C)
    chunk_state_kernel<<<BATCH * NHEADS * NC, 256, 0, stream>>>(xc, dtt, A_log, S, cumA);
    state_pass_kernel<<<BATCH * NHEADS, 256, 0, stream>>>(S, cumA);
    chunk_output_kernel<<<BATCH * NHEADS * NC, 256, 0, stream>>>(xc, dtt, S, cumA,
                                                                 D_param, yssm);
    // 5) RMSNorm + gate -> bf16
    rms_gate_kernel<<<BL, 256, 0, stream>>>(yssm, zx, norm_w, ygb);

    // 6) out_proj (bf16 MFMA)
    gemm_bf16_nt<64, 128, 1, 4><<<dim3(D_MODEL / 128, BL / 64), 256, 0, stream>>>(
        ygb, woutb, out, D_INNER, D_MODEL);
}

// Round 5
// 167.713 us; speedup vs baseline: 7.1145x; 1.0092x over previous
//
#include <hip/hip_runtime.h>
#include <hip/hip_bf16.h>
#include <math.h>

// Problem dims
#define D_MODEL   1024
#define D_INNER   2048
#define NHEADS    32
#define HEADDIM   64
#define D_STATE   64
#define CONV_DIM  2176            // D_INNER + 2*D_STATE
#define D_IN_PROJ 4256            // 2*D_INNER + 2*D_STATE + NHEADS
#define ZXLD      4352            // padded to 128
#define BATCH     2
#define SEQLEN    1024
#define BL        (BATCH * SEQLEN)
#define RMS_EPS   1.1920929e-07f

#define QCHUNK 64
#define NC     (SEQLEN / QCHUNK)

typedef __attribute__((ext_vector_type(8))) short short8;
typedef __attribute__((ext_vector_type(4))) float f32x4;
typedef __attribute__((ext_vector_type(8))) unsigned short ushort8v;
typedef __attribute__((ext_vector_type(4))) unsigned short ushort4v;

__device__ __forceinline__ unsigned short f2bf(float f) {
    unsigned u = __builtin_bit_cast(unsigned, f);
    unsigned r = u + 0x7FFFu + ((u >> 16) & 1u);   // RTNE
    return (unsigned short)(r >> 16);
}
__device__ __forceinline__ float bf2f(unsigned short u) {
    unsigned v = ((unsigned)u) << 16;
    return __builtin_bit_cast(float, v);
}
__device__ __forceinline__ void gload_lds16(const void* g, void* l) {
    __builtin_amdgcn_global_load_lds(
        (const __attribute__((address_space(1))) void*)g,
        (__attribute__((address_space(3))) void*)l, 16, 0, 0);
}

#define MFMA_BF16 __builtin_amdgcn_mfma_f32_16x16x32_bf16

// ---------------------------------------------------------------------------
// bf16 MFMA GEMM, NT: C[m,n] = sum_k A[m,k]*B[n,k]  (m97 structure)
// OBF16: write bf16 output instead of fp32.
// ---------------------------------------------------------------------------
template<int BM, int BN, int WR, int WC, bool OBF16>
__global__ __launch_bounds__(256) void gemm_bf16_nt(
    const unsigned short* __restrict__ A, const unsigned short* __restrict__ B,
    void* __restrict__ Cv, int K, int ldc)
{
    constexpr int RM = BM / WR;
    constexpr int RN = BN / WC;
    constexpr int MF = RM / 16;
    constexpr int NF = RN / 16;
    constexpr int GA = BM / 64;
    constexpr int GB = BN / 64;

    __shared__ unsigned short As[BM][32];
    __shared__ unsigned short Bs[BN][32];

    const int tid  = threadIdx.x;
    const int lane = tid & 63;
    const int w    = tid >> 6;
    const int wm   = w / WC;
    const int wn   = w % WC;
    const int m0   = blockIdx.y * BM;
    const int n0   = blockIdx.x * BN;

    const int lrow = lane >> 2;
    const int lcol = (lane & 3) * 8;

    f32x4 acc[MF][NF];
#pragma unroll
    for (int mi = 0; mi < MF; ++mi)
#pragma unroll
        for (int ni = 0; ni < NF; ++ni) acc[mi][ni] = (f32x4){0.f, 0.f, 0.f, 0.f};

    for (int k0 = 0; k0 < K; k0 += 32) {
        __syncthreads();
#pragma unroll
        for (int q = 0; q < GA; ++q) {
            const int g = w * GA + q;
            const unsigned short* gp = A + (size_t)(m0 + g * 16 + lrow) * K + k0 + lcol;
            gload_lds16(gp, &As[g * 16][0]);
        }
#pragma unroll
        for (int q = 0; q < GB; ++q) {
            const int g = w * GB + q;
            const unsigned short* gp = B + (size_t)(n0 + g * 16 + lrow) * K + k0 + lcol;
            gload_lds16(gp, &Bs[g * 16][0]);
        }
        __syncthreads();

        short8 av[MF], bv[NF];
#pragma unroll
        for (int mi = 0; mi < MF; ++mi)
            av[mi] = *(const short8*)&As[wm * RM + mi * 16 + (lane & 15)][(lane >> 4) * 8];
#pragma unroll
        for (int ni = 0; ni < NF; ++ni)
            bv[ni] = *(const short8*)&Bs[wn * RN + ni * 16 + (lane & 15)][(lane >> 4) * 8];
#pragma unroll
        for (int mi = 0; mi < MF; ++mi)
#pragma unroll
            for (int ni = 0; ni < NF; ++ni)
                acc[mi][ni] = MFMA_BF16(av[mi], bv[ni], acc[mi][ni], 0, 0, 0);
    }

    const int crow = (lane >> 4) * 4;
    const int ccol = lane & 15;
#pragma unroll
    for (int mi = 0; mi < MF; ++mi)
#pragma unroll
        for (int ni = 0; ni < NF; ++ni) {
            const int row0 = m0 + wm * RM + mi * 16 + crow;
            const int col  = n0 + wn * RN + ni * 16 + ccol;
#pragma unroll
            for (int r = 0; r < 4; ++r) {
                if constexpr (OBF16) {
                    ((unsigned short*)Cv)[(size_t)(row0 + r) * ldc + col] =
                        f2bf(acc[mi][ni][r]);
                } else {
                    ((float*)Cv)[(size_t)(row0 + r) * ldc + col] = acc[mi][ni][r];
                }
            }
        }
}

// ---------------------------------------------------------------------------
// fp32 -> bf16 casts
// ---------------------------------------------------------------------------
__global__ __launch_bounds__(256) void cast_bf16_kernel(
    const float* __restrict__ src, unsigned short* __restrict__ dst, int n4)
{
    const int i = (blockIdx.x * 256 + threadIdx.x);
    if (i >= n4) return;
    float4 v = *(const float4*)(src + (size_t)i * 4);
    ushort4 o;
    o.x = f2bf(v.x); o.y = f2bf(v.y); o.z = f2bf(v.z); o.w = f2bf(v.w);
    *(ushort4*)(dst + (size_t)i * 4) = o;
}

__global__ __launch_bounds__(256) void cast_win_pad_kernel(
    const float* __restrict__ src, unsigned short* __restrict__ dst)
{
    const int i = (blockIdx.x * 256 + threadIdx.x);
    if (i >= ZXLD * D_MODEL / 4) return;
    const int e0 = i * 4;
    const int row = e0 >> 10;
    ushort4 o = {0, 0, 0, 0};
    if (row < D_IN_PROJ) {
        float4 v = *(const float4*)(src + (size_t)e0);
        o.x = f2bf(v.x); o.y = f2bf(v.y); o.z = f2bf(v.z); o.w = f2bf(v.w);
    }
    *(ushort4*)(dst + (size_t)e0) = o;
}

// ---------------------------------------------------------------------------
// dt = softplus(dt_raw + dt_bias) from bf16 zx, transposed: dtt[b][h][l]
// ---------------------------------------------------------------------------
__global__ __launch_bounds__(256) void dt_softplus_kernel(
    const unsigned short* __restrict__ zxb, const float* __restrict__ dt_bias,
    float* __restrict__ dtt)
{
    const int idx = blockIdx.x * 256 + threadIdx.x;
    const int m = idx >> 5;
    const int hd = idx & 31;
    const int b = m >> 10;
    const int l = m & (SEQLEN - 1);
    const float v = bf2f(zxb[(size_t)m * ZXLD + (D_INNER + CONV_DIM) + hd]) + dt_bias[hd];
    const float sp = (v > 20.f) ? v : log1pf(expf(v));
    dtt[((size_t)b * NHEADS + hd) * SEQLEN + l] = sp;
}

// ---------------------------------------------------------------------------
// Fused conv(4-tap causal)+silu staging: reads bf16 zx rows [l0-3, l0+64),
// conv channels [ch0+q .. ch0+q+16) per thread, writes bf16 LDS tile [64][72].
// T=false: lds[row][ch-ch0];  T=true: lds[ch-ch0][row] (optionally row-scaled).
// ---------------------------------------------------------------------------
template<bool T>
__device__ __forceinline__ void stage_conv64(
    const unsigned short* __restrict__ zxb, int grow0, int l0, int ch0,
    const float* __restrict__ conv_w, const float* __restrict__ conv_b,
    unsigned short (*lds)[72], int tid, const float* __restrict__ rowscale)
{
    const int r = tid >> 2;            // output row within chunk
    const int q = (tid & 3) * 16;      // channel offset within 64-col tile
    float in[4][16];
#pragma unroll
    for (int k = 0; k < 4; ++k) {
        const int ll = l0 + r - 3 + k;
        if (ll >= 0) {
            const unsigned short* src =
                zxb + (size_t)(grow0 + r - 3 + k) * ZXLD + (D_INNER + ch0 + q);
            ushort8v v0 = *(const ushort8v*)(src);
            ushort8v v1 = *(const ushort8v*)(src + 8);
#pragma unroll
            for (int j = 0; j < 8; ++j) { in[k][j] = bf2f(v0[j]); in[k][8 + j] = bf2f(v1[j]); }
        } else {
#pragma unroll
            for (int j = 0; j < 16; ++j) in[k][j] = 0.f;
        }
    }
    const float sc = rowscale ? rowscale[r] : 1.f;
#pragma unroll
    for (int j = 0; j < 16; ++j) {
        const int ch = ch0 + q + j;
        const float4 wv = *(const float4*)(conv_w + ch * 4);
        float acc = conv_b[ch];
        acc = fmaf(in[0][j], wv.x, acc);
        acc = fmaf(in[1][j], wv.y, acc);
        acc = fmaf(in[2][j], wv.z, acc);
        acc = fmaf(in[3][j], wv.w, acc);
        const float v = (acc / (1.f + expf(-acc))) * sc;
        if (T) lds[q + j][r] = f2bf(v);
        else   lds[r][q + j] = f2bf(v);
    }
}

// transposed stage of a bf16 64x64 tile (row-major src, stride 64)
__device__ __forceinline__ void stage_bf16T(
    const unsigned short* __restrict__ src, unsigned short (*lds)[72], int tid)
{
    const int r = tid >> 2, q = (tid & 3) * 16;
    const unsigned short* s = src + (size_t)r * 64 + q;
    ushort8v v0 = *(const ushort8v*)(s);
    ushort8v v1 = *(const ushort8v*)(s + 8);
#pragma unroll
    for (int j = 0; j < 8; ++j) { lds[q + j][r] = v0[j]; lds[q + 8 + j][r] = v1[j]; }
}

// ---------------------------------------------------------------------------
// Phase A (MFMA): S[n,p] = sum_t (w_t*B[t,n]) * X[t,p]; conv+silu fused into
// staging. S written bf16 [n][p].
// ---------------------------------------------------------------------------
__global__ __launch_bounds__(256) void chunk_state_kernel(
    const unsigned short* __restrict__ zxb, const float* __restrict__ dtt,
    const float* __restrict__ A_log, const float* __restrict__ conv_w,
    const float* __restrict__ conv_b,
    unsigned short* __restrict__ Sintra, float* __restrict__ cumA)
{
    const int bid = blockIdx.x;
    const int c = bid & (NC - 1);
    const int h = (bid >> 4) & (NHEADS - 1);
    const int b = bid >> 9;
    const int tid = threadIdx.x;
    const int lane = tid & 63;
    const int w = tid >> 6;

    __shared__ unsigned short sXT[64][72];
    __shared__ unsigned short sBT[64][72];
    __shared__ float sw[64];

    const int l0 = c * QCHUNK;
    const int grow0 = b * SEQLEN + l0;

    stage_conv64<true>(zxb, grow0, l0, h * HEADDIM, conv_w, conv_b, sXT, tid, nullptr);

    if (tid < QCHUNK) {
        const float A = -expf(A_log[h]);
        const float dtv = dtt[((size_t)b * NHEADS + h) * SEQLEN + l0 + tid];
        float cum = dtv * A;
#pragma unroll
        for (int off = 1; off < 64; off <<= 1) {
            const float o = __shfl_up(cum, off, 64);
            if (tid >= off) cum += o;
        }
        const float cum_end = __shfl(cum, 63, 64);
        sw[tid] = expf(cum_end - cum) * dtv;
        cumA[(size_t)bid * QCHUNK + tid] = cum;
    }
    __syncthreads();   // sw ready

    stage_conv64<true>(zxb, grow0, l0, D_INNER, conv_w, conv_b, sBT, tid, sw);
    __syncthreads();

    const int fr = lane & 15;
    const int ko = (lane >> 4) * 8;
    short8 a0 = *(const short8*)&sBT[w * 16 + fr][ko];
    short8 a1 = *(const short8*)&sBT[w * 16 + fr][ko + 32];

    unsigned short* sout = Sintra + (size_t)bid * (D_STATE * HEADDIM);
    const int nrow = w * 16 + (lane >> 4) * 4;
#pragma unroll
    for (int j = 0; j < 4; ++j) {
        short8 b0 = *(const short8*)&sXT[j * 16 + fr][ko];
        short8 b1 = *(const short8*)&sXT[j * 16 + fr][ko + 32];
        f32x4 a = (f32x4){0.f, 0.f, 0.f, 0.f};
        a = MFMA_BF16(a0, b0, a, 0, 0, 0);
        a = MFMA_BF16(a1, b1, a, 0, 0, 0);
        const int p = j * 16 + fr;
#pragma unroll
        for (int r = 0; r < 4; ++r)
            sout[(size_t)(nrow + r) * HEADDIM + p] = f2bf(a[r]);
    }
}

// ---------------------------------------------------------------------------
// Phase B: inter-chunk recurrence on bf16 S, elementwise re-grid:
// 256 blocks x 256 threads, 4 state elems per thread, depth-1 prefetch.
// ---------------------------------------------------------------------------
__global__ __launch_bounds__(256) void state_pass_kernel(
    unsigned short* __restrict__ S, const float* __restrict__ cumA)
{
    const int gid = blockIdx.x * 256 + threadIdx.x;     // 65536 threads
    const int bh = gid >> 10;                            // 4096 elems / (b,h)
    const int e0 = (gid & 1023) * 4;

    float run[4] = {0.f, 0.f, 0.f, 0.f};
    unsigned short* base = S + (size_t)bh * NC * (D_STATE * HEADDIM) + e0;

    ushort4v pre = *(const ushort4v*)base;
    float gpre = expf(cumA[((size_t)bh * NC) * QCHUNK + (QCHUNK - 1)]);

    for (int c = 0; c < NC; ++c) {
        const ushort4v cur = pre;
        const float g = gpre;
        if (c + 1 < NC) {
            pre = *(const ushort4v*)(base + (size_t)(c + 1) * (D_STATE * HEADDIM));
            gpre = expf(cumA[((size_t)bh * NC + c + 1) * QCHUNK + (QCHUNK - 1)]);
        }
        ushort4v o;
#pragma unroll
        for (int j = 0; j < 4; ++j) o[j] = f2bf(run[j]);
        *(ushort4v*)(base + (size_t)c * (D_STATE * HEADDIM)) = o;
#pragma unroll
        for (int j = 0; j < 4; ++j) run[j] = fmaf(g, run[j], bf2f(cur[j]));
    }
}

// ---------------------------------------------------------------------------
// Phase C (MFMA): G = C.B^T; M = mask(G)*exp(dcum)*dt; Y = M.X + exp(cum)*C.SP + D*x
// conv+silu fused into staging; SP read bf16.
// ---------------------------------------------------------------------------
__global__ __launch_bounds__(256) void chunk_output_kernel(
    const unsigned short* __restrict__ zxb, const float* __restrict__ dtt,
    const unsigned short* __restrict__ SP, const float* __restrict__ cumA,
    const float* __restrict__ conv_w, const float* __restrict__ conv_b,
    const float* __restrict__ D_param, float* __restrict__ y)
{
    const int bid = blockIdx.x;
    const int c = bid & (NC - 1);
    const int h = (bid >> 4) & (NHEADS - 1);
    const int b = bid >> 9;
    const int tid = threadIdx.x;
    const int lane = tid & 63;
    const int w = tid >> 6;

    __shared__ unsigned short sC[64][72];
    __shared__ unsigned short sB[64][72];
    __shared__ unsigned short sXT[64][72];
    __shared__ unsigned short sSPT[64][72];
    __shared__ unsigned short sM[64][72];
    __shared__ float scum[64], sdt[64];

    const int l0 = c * QCHUNK;
    const int grow0 = b * SEQLEN + l0;

    stage_conv64<false>(zxb, grow0, l0, D_INNER + D_STATE, conv_w, conv_b, sC, tid, nullptr);
    stage_conv64<false>(zxb, grow0, l0, D_INNER, conv_w, conv_b, sB, tid, nullptr);
    stage_conv64<true >(zxb, grow0, l0, h * HEADDIM, conv_w, conv_b, sXT, tid, nullptr);
    stage_bf16T(SP + (size_t)bid * (D_STATE * HEADDIM), sSPT, tid);
    if (tid < QCHUNK) {
        scum[tid] = cumA[(size_t)bid * QCHUNK + tid];
        sdt[tid] = dtt[((size_t)b * NHEADS + h) * SEQLEN + l0 + tid];
    }
    __syncthreads();

    const int fr = lane & 15;
    const int ko = (lane >> 4) * 8;
    const int trow = w * 16 + (lane >> 4) * 4;

    short8 aC0 = *(const short8*)&sC[w * 16 + fr][ko];
    short8 aC1 = *(const short8*)&sC[w * 16 + fr][ko + 32];

    // --- G = C.B^T ---
    f32x4 g[4];
#pragma unroll
    for (int j = 0; j < 4; ++j) {
        short8 b0 = *(const short8*)&sB[j * 16 + fr][ko];
        short8 b1 = *(const short8*)&sB[j * 16 + fr][ko + 32];
        f32x4 a = (f32x4){0.f, 0.f, 0.f, 0.f};
        a = MFMA_BF16(aC0, b0, a, 0, 0, 0);
        a = MFMA_BF16(aC1, b1, a, 0, 0, 0);
        g[j] = a;
    }

    // --- decay mask -> sM (bf16) ---
    float ct[4];
#pragma unroll
    for (int r = 0; r < 4; ++r) ct[r] = scum[trow + r];
#pragma unroll
    for (int j = 0; j < 4; ++j) {
        const int s = j * 16 + fr;
        const float cs = scum[s], ds = sdt[s];
#pragma unroll
        for (int r = 0; r < 4; ++r) {
            const int t = trow + r;
            const float m = (s <= t) ? g[j][r] * expf(ct[r] - cs) * ds : 0.f;
            sM[t][s] = f2bf(m);
        }
    }
    __syncthreads();

    // --- Y1 = M.X, Y2 = C.SP ---
    short8 aM0 = *(const short8*)&sM[w * 16 + fr][ko];
    short8 aM1 = *(const short8*)&sM[w * 16 + fr][ko + 32];
    f32x4 y1[4], y2[4];
#pragma unroll
    for (int j = 0; j < 4; ++j) {
        short8 bx0 = *(const short8*)&sXT[j * 16 + fr][ko];
        short8 bx1 = *(const short8*)&sXT[j * 16 + fr][ko + 32];
        f32x4 a = (f32x4){0.f, 0.f, 0.f, 0.f};
        a = MFMA_BF16(aM0, bx0, a, 0, 0, 0);
        a = MFMA_BF16(aM1, bx1, a, 0, 0, 0);
        y1[j] = a;
        short8 bs0 = *(const short8*)&sSPT[j * 16 + fr][ko];
        short8 bs1 = *(const short8*)&sSPT[j * 16 + fr][ko + 32];
        f32x4 a2 = (f32x4){0.f, 0.f, 0.f, 0.f};
        a2 = MFMA_BF16(aC0, bs0, a2, 0, 0, 0);
        a2 = MFMA_BF16(aC1, bs1, a2, 0, 0, 0);
        y2[j] = a2;
    }

    const float Dp = D_param[h];
    float et[4];
#pragma unroll
    for (int r = 0; r < 4; ++r) et[r] = expf(ct[r]);
    float* ybase = y + (((size_t)b * SEQLEN + l0) * D_INNER) + h * HEADDIM;
#pragma unroll
    for (int j = 0; j < 4; ++j) {
        const int p = j * 16 + fr;
#pragma unroll
        for (int r = 0; r < 4; ++r) {
            const int t = trow + r;
            const float xv = bf2f(sXT[p][t]);
            ybase[(size_t)t * D_INNER + p] = y1[j][r] + et[r] * y2[j][r] + Dp * xv;
        }
    }
}

// ---------------------------------------------------------------------------
// RMSNorm * norm_w * silu(z) -> bf16; z read from bf16 zx
// ---------------------------------------------------------------------------
__global__ __launch_bounds__(256) void rms_gate_kernel(
    const float* __restrict__ y, const unsigned short* __restrict__ zxb,
    const float* __restrict__ norm_w, unsigned short* __restrict__ out)
{
    const int m = blockIdx.x;
    const int tid = threadIdx.x;
    const float* yr = y + (size_t)m * D_INNER;
    const unsigned short* zr = zxb + (size_t)m * ZXLD;

    float4 v0 = *(const float4*)(yr + tid * 8);
    float4 v1 = *(const float4*)(yr + tid * 8 + 4);
    float yv[8] = {v0.x, v0.y, v0.z, v0.w, v1.x, v1.y, v1.z, v1.w};
    float ss = 0.f;
#pragma unroll
    for (int j = 0; j < 8; ++j) ss += yv[j] * yv[j];
#pragma unroll
    for (int off = 32; off > 0; off >>= 1) ss += __shfl_xor(ss, off, 64);
    __shared__ float sred[4];
    if ((tid & 63) == 0) sred[tid >> 6] = ss;
    __syncthreads();
    const float tot = sred[0] + sred[1] + sred[2] + sred[3];
    const float inv = rsqrtf(tot * (1.f / D_INNER) + RMS_EPS);

    ushort8v zv8 = *(const ushort8v*)(zr + tid * 8);
    const float* nw = norm_w + tid * 8;
    ushort8v o;
#pragma unroll
    for (int j = 0; j < 8; ++j) {
        const float zz = bf2f(zv8[j]);
        const float sig = 1.f / (1.f + expf(-zz));
        o[j] = f2bf(yv[j] * inv * nw[j] * (zz * sig));
    }
    *(ushort8v*)(out + (size_t)m * D_INNER + tid * 8) = o;
}

// ---------------------------------------------------------------------------
// Workspace layout (bytes, 16-aligned), ~69 MB total:
//   zxb   bf16 BL*ZXLD          17,825,792
//   dtt   f32  B*H*L                262,144
//   cumA  f32  B*H*NC*64            262,144
//   Sb    bf16 B*H*NC*4096       8,388,608
//   yssm  f32  BL*D_INNER       16,777,216
//   xb    bf16 BL*D_MODEL        4,194,304
//   winb  bf16 ZXLD*D_MODEL      8,912,896
//   woutb bf16 D_MODEL*D_INNER   4,194,304
//   ygb   bf16 BL*D_INNER        8,388,608
// ---------------------------------------------------------------------------
extern "C" void kernel_launch(void* const* d_in, const int* in_sizes, int n_in,
                              void* d_out, int out_size, void* d_ws, size_t ws_size,
                              hipStream_t stream)
{
    const float* x       = (const float*)d_in[0];
    const float* W_in    = (const float*)d_in[1];
    const float* conv_w  = (const float*)d_in[2];
    const float* conv_b  = (const float*)d_in[3];
    const float* dt_bias = (const float*)d_in[4];
    const float* A_log   = (const float*)d_in[5];
    const float* D_param = (const float*)d_in[6];
    const float* norm_w  = (const float*)d_in[7];
    const float* W_out   = (const float*)d_in[8];
    float* out = (float*)d_out;

    char* p = (char*)d_ws;
    unsigned short* zxb   = (unsigned short*)p;  p += (size_t)BL * ZXLD * 2;
    float*          dtt   = (float*)p;           p += (size_t)BATCH * NHEADS * SEQLEN * 4;
    float*          cumA  = (float*)p;           p += (size_t)BATCH * NHEADS * SEQLEN * 4;
    unsigned short* Sb    = (unsigned short*)p;  p += (size_t)BATCH * NHEADS * NC * D_STATE * HEADDIM * 2;
    float*          yssm  = (float*)p;           p += (size_t)BL * D_INNER * 4;
    unsigned short* xb    = (unsigned short*)p;  p += (size_t)BL * D_MODEL * 2;
    unsigned short* winb  = (unsigned short*)p;  p += (size_t)ZXLD * D_MODEL * 2;
    unsigned short* woutb = (unsigned short*)p;  p += (size_t)D_MODEL * D_INNER * 2;
    unsigned short* ygb   = (unsigned short*)p;

    // 0) casts
    cast_bf16_kernel<<<(BL * D_MODEL / 4 + 255) / 256, 256, 0, stream>>>(
        x, xb, BL * D_MODEL / 4);
    cast_win_pad_kernel<<<(ZXLD * D_MODEL / 4 + 255) / 256, 256, 0, stream>>>(W_in, winb);
    cast_bf16_kernel<<<(D_MODEL * D_INNER / 4 + 255) / 256, 256, 0, stream>>>(
        W_out, woutb, D_MODEL * D_INNER / 4);

    // 1) in_proj (bf16 MFMA, bf16 output)
    gemm_bf16_nt<128, 128, 2, 2, true><<<dim3(ZXLD / 128, BL / 128), 256, 0, stream>>>(
        xb, winb, zxb, D_MODEL, ZXLD);

    // 2) dt softplus
    dt_softplus_kernel<<<(BL * NHEADS) / 256, 256, 0, stream>>>(zxb, dt_bias, dtt);
    // 3) chunked SSM scan (conv+silu fused into staging)
    chunk_state_kernel<<<BATCH * NHEADS * NC, 256, 0, stream>>>(
        zxb, dtt, A_log, conv_w, conv_b, Sb, cumA);
    state_pass_kernel<<<256, 256, 0, stream>>>(Sb, cumA);
    chunk_output_kernel<<<BATCH * NHEADS * NC, 256, 0, stream>>>(
        zxb, dtt, Sb, cumA, conv_w, conv_b, D_param, yssm);
    // 4) RMSNorm + gate -> bf16
    rms_gate_kernel<<<BL, 256, 0, stream>>>(yssm, zxb, norm_w, ygb);

    // 5) out_proj (bf16 MFMA, fp32 output)
    gemm_bf16_nt<64, 128, 1, 4, false><<<dim3(D_MODEL / 128, BL / 64), 256, 0, stream>>>(
        ygb, woutb, out, D_INNER, D_MODEL);
}

// Round 6
// 135.817 us; speedup vs baseline: 8.7853x; 1.2349x over previous
//
#include <hip/hip_runtime.h>
#include <hip/hip_bf16.h>
#include <math.h>

// Problem dims
#define D_MODEL   1024
#define D_INNER   2048
#define NHEADS    32
#define HEADDIM   64
#define D_STATE   64
#define CONV_DIM  2176            // D_INNER + 2*D_STATE
#define D_IN_PROJ 4256            // 2*D_INNER + 2*D_STATE + NHEADS
#define ZXLD      4352            // padded to 128
#define BATCH     2
#define SEQLEN    1024
#define BL        (BATCH * SEQLEN)
#define RMS_EPS   1.1920929e-07f

#define QCHUNK 64
#define NC     (SEQLEN / QCHUNK)

typedef __attribute__((ext_vector_type(8))) short short8;
typedef __attribute__((ext_vector_type(4))) float f32x4;
typedef __attribute__((ext_vector_type(8))) unsigned short ushort8v;
typedef __attribute__((ext_vector_type(4))) unsigned short ushort4v;

__device__ __forceinline__ unsigned short f2bf(float f) {
    unsigned u = __builtin_bit_cast(unsigned, f);
    unsigned r = u + 0x7FFFu + ((u >> 16) & 1u);   // RTNE
    return (unsigned short)(r >> 16);
}
__device__ __forceinline__ float bf2f(unsigned short u) {
    unsigned v = ((unsigned)u) << 16;
    return __builtin_bit_cast(float, v);
}
__device__ __forceinline__ void gload_lds16(const void* g, void* l) {
    __builtin_amdgcn_global_load_lds(
        (const __attribute__((address_space(1))) void*)g,
        (__attribute__((address_space(3))) void*)l, 16, 0, 0);
}

#define MFMA_BF16 __builtin_amdgcn_mfma_f32_16x16x32_bf16

// ---------------------------------------------------------------------------
// bf16 MFMA GEMM, NT: C[m,n] = sum_k A[m,k]*B[n,k]  (m97 structure)
// ---------------------------------------------------------------------------
template<int BM, int BN, int WR, int WC, bool OBF16>
__global__ __launch_bounds__(256) void gemm_bf16_nt(
    const unsigned short* __restrict__ A, const unsigned short* __restrict__ B,
    void* __restrict__ Cv, int K, int ldc)
{
    constexpr int RM = BM / WR;
    constexpr int RN = BN / WC;
    constexpr int MF = RM / 16;
    constexpr int NF = RN / 16;
    constexpr int GA = BM / 64;
    constexpr int GB = BN / 64;

    __shared__ unsigned short As[BM][32];
    __shared__ unsigned short Bs[BN][32];

    const int tid  = threadIdx.x;
    const int lane = tid & 63;
    const int w    = tid >> 6;
    const int wm   = w / WC;
    const int wn   = w % WC;
    const int m0   = blockIdx.y * BM;
    const int n0   = blockIdx.x * BN;

    const int lrow = lane >> 2;
    const int lcol = (lane & 3) * 8;

    f32x4 acc[MF][NF];
#pragma unroll
    for (int mi = 0; mi < MF; ++mi)
#pragma unroll
        for (int ni = 0; ni < NF; ++ni) acc[mi][ni] = (f32x4){0.f, 0.f, 0.f, 0.f};

    for (int k0 = 0; k0 < K; k0 += 32) {
        __syncthreads();
#pragma unroll
        for (int q = 0; q < GA; ++q) {
            const int g = w * GA + q;
            const unsigned short* gp = A + (size_t)(m0 + g * 16 + lrow) * K + k0 + lcol;
            gload_lds16(gp, &As[g * 16][0]);
        }
#pragma unroll
        for (int q = 0; q < GB; ++q) {
            const int g = w * GB + q;
            const unsigned short* gp = B + (size_t)(n0 + g * 16 + lrow) * K + k0 + lcol;
            gload_lds16(gp, &Bs[g * 16][0]);
        }
        __syncthreads();

        short8 av[MF], bv[NF];
#pragma unroll
        for (int mi = 0; mi < MF; ++mi)
            av[mi] = *(const short8*)&As[wm * RM + mi * 16 + (lane & 15)][(lane >> 4) * 8];
#pragma unroll
        for (int ni = 0; ni < NF; ++ni)
            bv[ni] = *(const short8*)&Bs[wn * RN + ni * 16 + (lane & 15)][(lane >> 4) * 8];
#pragma unroll
        for (int mi = 0; mi < MF; ++mi)
#pragma unroll
            for (int ni = 0; ni < NF; ++ni)
                acc[mi][ni] = MFMA_BF16(av[mi], bv[ni], acc[mi][ni], 0, 0, 0);
    }

    const int crow = (lane >> 4) * 4;
    const int ccol = lane & 15;
#pragma unroll
    for (int mi = 0; mi < MF; ++mi)
#pragma unroll
        for (int ni = 0; ni < NF; ++ni) {
            const int row0 = m0 + wm * RM + mi * 16 + crow;
            const int col  = n0 + wn * RN + ni * 16 + ccol;
#pragma unroll
            for (int r = 0; r < 4; ++r) {
                if constexpr (OBF16) {
                    ((unsigned short*)Cv)[(size_t)(row0 + r) * ldc + col] =
                        f2bf(acc[mi][ni][r]);
                } else {
                    ((float*)Cv)[(size_t)(row0 + r) * ldc + col] = acc[mi][ni][r];
                }
            }
        }
}

// ---------------------------------------------------------------------------
// fp32 -> bf16 casts
// ---------------------------------------------------------------------------
__global__ __launch_bounds__(256) void cast_bf16_kernel(
    const float* __restrict__ src, unsigned short* __restrict__ dst, int n4)
{
    const int i = (blockIdx.x * 256 + threadIdx.x);
    if (i >= n4) return;
    float4 v = *(const float4*)(src + (size_t)i * 4);
    ushort4 o;
    o.x = f2bf(v.x); o.y = f2bf(v.y); o.z = f2bf(v.z); o.w = f2bf(v.w);
    *(ushort4*)(dst + (size_t)i * 4) = o;
}

__global__ __launch_bounds__(256) void cast_win_pad_kernel(
    const float* __restrict__ src, unsigned short* __restrict__ dst)
{
    const int i = (blockIdx.x * 256 + threadIdx.x);
    if (i >= ZXLD * D_MODEL / 4) return;
    const int e0 = i * 4;
    const int row = e0 >> 10;
    ushort4 o = {0, 0, 0, 0};
    if (row < D_IN_PROJ) {
        float4 v = *(const float4*)(src + (size_t)e0);
        o.x = f2bf(v.x); o.y = f2bf(v.y); o.z = f2bf(v.z); o.w = f2bf(v.w);
    }
    *(ushort4*)(dst + (size_t)e0) = o;
}

// ---------------------------------------------------------------------------
// dt = softplus(dt_raw + dt_bias) from bf16 zx, transposed: dtt[b][h][l]
// ---------------------------------------------------------------------------
__global__ __launch_bounds__(256) void dt_softplus_kernel(
    const unsigned short* __restrict__ zxb, const float* __restrict__ dt_bias,
    float* __restrict__ dtt)
{
    const int idx = blockIdx.x * 256 + threadIdx.x;
    const int m = idx >> 5;
    const int hd = idx & 31;
    const int b = m >> 10;
    const int l = m & (SEQLEN - 1);
    const float v = bf2f(zxb[(size_t)m * ZXLD + (D_INNER + CONV_DIM) + hd]) + dt_bias[hd];
    const float sp = (v > 20.f) ? v : log1pf(__expf(v));
    dtt[((size_t)b * NHEADS + hd) * SEQLEN + l] = sp;
}

// ---------------------------------------------------------------------------
// conv_pre: single-pass conv(4-tap causal)+silu over the conv strip of zxb.
// Emits bf16 in the layouts the chunk kernels consume:
//   xTb[b][h][c][p][t]  transposed 64x64 x tiles   (8.4 MB)
//   Bcc[b][c][t][n]     natural B tiles            (256 KB)
//   BTc[b][c][n][t]     transposed B tiles         (256 KB)
//   Ccc[b][c][t][n]     natural C tiles            (256 KB)
// grid (NC, 17, BATCH): g<16 -> x channels [g*128,g*128+128) (heads 2g,2g+1);
// g==16 -> B (hh=0) and C (hh=1).
// ---------------------------------------------------------------------------
__global__ __launch_bounds__(256) void conv_pre_kernel(
    const unsigned short* __restrict__ zxb,
    const float* __restrict__ conv_w, const float* __restrict__ conv_b,
    unsigned short* __restrict__ xTb, unsigned short* __restrict__ Bcc,
    unsigned short* __restrict__ BTc, unsigned short* __restrict__ Ccc)
{
    const int c = blockIdx.x;
    const int g = blockIdx.y;
    const int b = blockIdx.z;
    const int tid = threadIdx.x;

    __shared__ unsigned short L[64][138];

    const int l0 = c * QCHUNK;
    const int grow0 = b * SEQLEN + l0;
    const int r = tid >> 2;             // row t within chunk
    const int q = (tid & 3) * 16;       // channel offset within 64-ch half

    for (int hh = 0; hh < 2; ++hh) {
        const int chbase = g * 128 + hh * 64;          // conv-space channel base
        // --- conv + silu for (row r, channels chbase+q .. +16) ---
        float in[4][16];
#pragma unroll
        for (int k = 0; k < 4; ++k) {
            const int ll = l0 + r - 3 + k;
            if (ll >= 0) {
                const unsigned short* src =
                    zxb + (size_t)(grow0 + r - 3 + k) * ZXLD + (D_INNER + chbase + q);
                ushort8v v0 = *(const ushort8v*)(src);
                ushort8v v1 = *(const ushort8v*)(src + 8);
#pragma unroll
                for (int j = 0; j < 8; ++j) { in[k][j] = bf2f(v0[j]); in[k][8 + j] = bf2f(v1[j]); }
            } else {
#pragma unroll
                for (int j = 0; j < 16; ++j) in[k][j] = 0.f;
            }
        }
        unsigned short o[16];
#pragma unroll
        for (int j = 0; j < 16; ++j) {
            const int ch = chbase + q + j;
            const float4 wv = *(const float4*)(conv_w + ch * 4);
            float a = conv_b[ch];
            a = fmaf(in[0][j], wv.x, a);
            a = fmaf(in[1][j], wv.y, a);
            a = fmaf(in[2][j], wv.z, a);
            a = fmaf(in[3][j], wv.w, a);
            o[j] = f2bf(a / (1.f + __expf(-a)));
        }

        const bool isB = (g == 16) && (hh == 0);
        const bool isC = (g == 16) && (hh == 1);
        const size_t ctile = ((size_t)b * NC + c) * 4096;

        if (isB || isC) {   // natural store [t][n]
            unsigned short* dst = (isB ? Bcc : Ccc) + ctile + (size_t)r * 64 + q;
            ushort8v w0, w1;
#pragma unroll
            for (int j = 0; j < 8; ++j) { w0[j] = o[j]; w1[j] = o[8 + j]; }
            *(ushort8v*)dst = w0;
            *(ushort8v*)(dst + 8) = w1;
        }
        if (!isC) {         // transposed output needed (x tiles, BT)
            // write natural to LDS
#pragma unroll
            for (int j = 0; j < 8; ++j) { L[r][q + j] = o[j]; L[r][q + 8 + j] = o[8 + j]; }
            __syncthreads();
            // transpose readout: out row = channel cc, cols = t
            const int cc = tid >> 2;
            const int tseg = (tid & 3) * 16;
            unsigned short tv[16];
#pragma unroll
            for (int j = 0; j < 16; ++j) tv[j] = L[tseg + j][cc];
            unsigned short* dstT;
            if (isB) dstT = BTc + ctile + (size_t)cc * 64 + tseg;
            else {
                const int h = g * 2 + hh;
                dstT = xTb + (((size_t)b * NHEADS + h) * NC + c) * 4096 + (size_t)cc * 64 + tseg;
            }
            ushort8v w0, w1;
#pragma unroll
            for (int j = 0; j < 8; ++j) { w0[j] = tv[j]; w1[j] = tv[8 + j]; }
            *(ushort8v*)dstT = w0;
            *(ushort8v*)(dstT + 8) = w1;
        }
        __syncthreads();
    }
}

// ---------------------------------------------------------------------------
// Phase A (MFMA): S[n,p] = sum_t B[t,n] * (w_t*X[t,p]); identity staging from
// precomputed transposed bf16 tiles. S written bf16 [n][p].
// ---------------------------------------------------------------------------
__global__ __launch_bounds__(256) void chunk_state_kernel(
    const unsigned short* __restrict__ xTb, const unsigned short* __restrict__ BTc,
    const float* __restrict__ dtt, const float* __restrict__ A_log,
    unsigned short* __restrict__ Sintra, float* __restrict__ cumA)
{
    const int bid = blockIdx.x;
    const int c = bid & (NC - 1);
    const int h = (bid >> 4) & (NHEADS - 1);
    const int b = bid >> 9;
    const int tid = threadIdx.x;
    const int lane = tid & 63;
    const int w = tid >> 6;

    __shared__ unsigned short sXT[64][72];
    __shared__ unsigned short sBT[64][72];
    __shared__ float sw[64];

    if (tid < QCHUNK) {
        const float A = -__expf(A_log[h]);
        const float dtv = dtt[((size_t)b * NHEADS + h) * SEQLEN + c * QCHUNK + tid];
        float cum = dtv * A;
#pragma unroll
        for (int off = 1; off < 64; off <<= 1) {
            const float o = __shfl_up(cum, off, 64);
            if (tid >= off) cum += o;
        }
        const float cum_end = __shfl(cum, 63, 64);
        sw[tid] = __expf(cum_end - cum) * dtv;
        cumA[(size_t)bid * QCHUNK + tid] = cum;
    }
    __syncthreads();

    {   // stage XT (w-scaled) and BT (identity)
        const int r = tid >> 2, q = (tid & 3) * 16;
        const unsigned short* xs =
            xTb + (((size_t)b * NHEADS + h) * NC + c) * 4096 + (size_t)r * 64 + q;
        ushort8v v0 = *(const ushort8v*)(xs);
        ushort8v v1 = *(const ushort8v*)(xs + 8);
        ushort8v s0, s1;
#pragma unroll
        for (int j = 0; j < 8; ++j) {
            s0[j] = f2bf(bf2f(v0[j]) * sw[q + j]);
            s1[j] = f2bf(bf2f(v1[j]) * sw[q + 8 + j]);
        }
        *(ushort8v*)&sXT[r][q] = s0;
        *(ushort8v*)&sXT[r][q + 8] = s1;

        const unsigned short* bs =
            BTc + ((size_t)b * NC + c) * 4096 + (size_t)r * 64 + q;
        *(ushort8v*)&sBT[r][q]     = *(const ushort8v*)(bs);
        *(ushort8v*)&sBT[r][q + 8] = *(const ushort8v*)(bs + 8);
    }
    __syncthreads();

    const int fr = lane & 15;
    const int ko = (lane >> 4) * 8;
    short8 a0 = *(const short8*)&sBT[w * 16 + fr][ko];
    short8 a1 = *(const short8*)&sBT[w * 16 + fr][ko + 32];

    unsigned short* sout = Sintra + (size_t)bid * (D_STATE * HEADDIM);
    const int nrow = w * 16 + (lane >> 4) * 4;
#pragma unroll
    for (int j = 0; j < 4; ++j) {
        short8 b0 = *(const short8*)&sXT[j * 16 + fr][ko];
        short8 b1 = *(const short8*)&sXT[j * 16 + fr][ko + 32];
        f32x4 a = (f32x4){0.f, 0.f, 0.f, 0.f};
        a = MFMA_BF16(a0, b0, a, 0, 0, 0);
        a = MFMA_BF16(a1, b1, a, 0, 0, 0);
        const int p = j * 16 + fr;
#pragma unroll
        for (int r = 0; r < 4; ++r)
            sout[(size_t)(nrow + r) * HEADDIM + p] = f2bf(a[r]);
    }
}

// ---------------------------------------------------------------------------
// Phase B: inter-chunk recurrence on bf16 S (elementwise, 256 blocks)
// ---------------------------------------------------------------------------
__global__ __launch_bounds__(256) void state_pass_kernel(
    unsigned short* __restrict__ S, const float* __restrict__ cumA)
{
    const int gid = blockIdx.x * 256 + threadIdx.x;
    const int bh = gid >> 10;
    const int e0 = (gid & 1023) * 4;

    float run[4] = {0.f, 0.f, 0.f, 0.f};
    unsigned short* base = S + (size_t)bh * NC * (D_STATE * HEADDIM) + e0;

    ushort4v pre = *(const ushort4v*)base;
    float gpre = __expf(cumA[((size_t)bh * NC) * QCHUNK + (QCHUNK - 1)]);

    for (int c = 0; c < NC; ++c) {
        const ushort4v cur = pre;
        const float g = gpre;
        if (c + 1 < NC) {
            pre = *(const ushort4v*)(base + (size_t)(c + 1) * (D_STATE * HEADDIM));
            gpre = __expf(cumA[((size_t)bh * NC + c + 1) * QCHUNK + (QCHUNK - 1)]);
        }
        ushort4v o;
#pragma unroll
        for (int j = 0; j < 4; ++j) o[j] = f2bf(run[j]);
        *(ushort4v*)(base + (size_t)c * (D_STATE * HEADDIM)) = o;
#pragma unroll
        for (int j = 0; j < 4; ++j) run[j] = fmaf(g, run[j], bf2f(cur[j]));
    }
}

// ---------------------------------------------------------------------------
// Phase C (MFMA): G = C.B^T; M = mask(G)*exp(dcum)*dt; Y = M.X + exp(cum)*C.SP + D*x
// All staging = identity copies from precomputed bf16 tiles; y out bf16.
// ---------------------------------------------------------------------------
__global__ __launch_bounds__(256) void chunk_output_kernel(
    const unsigned short* __restrict__ xTb, const unsigned short* __restrict__ Bcc,
    const unsigned short* __restrict__ Ccc, const float* __restrict__ dtt,
    const unsigned short* __restrict__ SP, const float* __restrict__ cumA,
    const float* __restrict__ D_param, unsigned short* __restrict__ y)
{
    const int bid = blockIdx.x;
    const int c = bid & (NC - 1);
    const int h = (bid >> 4) & (NHEADS - 1);
    const int b = bid >> 9;
    const int tid = threadIdx.x;
    const int lane = tid & 63;
    const int w = tid >> 6;

    __shared__ unsigned short sC[64][72];
    __shared__ unsigned short sB[64][72];
    __shared__ unsigned short sXT[64][72];
    __shared__ unsigned short sSPT[64][72];
    __shared__ unsigned short sM[64][72];
    __shared__ float scum[64], sdt[64];

    const size_t ctile = ((size_t)b * NC + c) * 4096;
    {
        const int r = tid >> 2, q = (tid & 3) * 16;
        const unsigned short* cs = Ccc + ctile + (size_t)r * 64 + q;
        *(ushort8v*)&sC[r][q]     = *(const ushort8v*)(cs);
        *(ushort8v*)&sC[r][q + 8] = *(const ushort8v*)(cs + 8);
        const unsigned short* bs = Bcc + ctile + (size_t)r * 64 + q;
        *(ushort8v*)&sB[r][q]     = *(const ushort8v*)(bs);
        *(ushort8v*)&sB[r][q + 8] = *(const ushort8v*)(bs + 8);
        const unsigned short* xs =
            xTb + (((size_t)b * NHEADS + h) * NC + c) * 4096 + (size_t)r * 64 + q;
        *(ushort8v*)&sXT[r][q]     = *(const ushort8v*)(xs);
        *(ushort8v*)&sXT[r][q + 8] = *(const ushort8v*)(xs + 8);
        // SP transpose: [n][p] -> lds[p][n]
        const unsigned short* ss = SP + (size_t)bid * (D_STATE * HEADDIM) + (size_t)r * 64 + q;
        ushort8v v0 = *(const ushort8v*)(ss);
        ushort8v v1 = *(const ushort8v*)(ss + 8);
#pragma unroll
        for (int j = 0; j < 8; ++j) { sSPT[q + j][r] = v0[j]; sSPT[q + 8 + j][r] = v1[j]; }
    }
    if (tid < QCHUNK) {
        scum[tid] = cumA[(size_t)bid * QCHUNK + tid];
        sdt[tid] = dtt[((size_t)b * NHEADS + h) * SEQLEN + c * QCHUNK + tid];
    }
    __syncthreads();

    const int fr = lane & 15;
    const int ko = (lane >> 4) * 8;
    const int trow = w * 16 + (lane >> 4) * 4;

    short8 aC0 = *(const short8*)&sC[w * 16 + fr][ko];
    short8 aC1 = *(const short8*)&sC[w * 16 + fr][ko + 32];

    // --- G = C.B^T ---
    f32x4 g[4];
#pragma unroll
    for (int j = 0; j < 4; ++j) {
        short8 b0 = *(const short8*)&sB[j * 16 + fr][ko];
        short8 b1 = *(const short8*)&sB[j * 16 + fr][ko + 32];
        f32x4 a = (f32x4){0.f, 0.f, 0.f, 0.f};
        a = MFMA_BF16(aC0, b0, a, 0, 0, 0);
        a = MFMA_BF16(aC1, b1, a, 0, 0, 0);
        g[j] = a;
    }

    // --- decay mask -> sM (bf16) ---
    float ct[4];
#pragma unroll
    for (int r = 0; r < 4; ++r) ct[r] = scum[trow + r];
#pragma unroll
    for (int j = 0; j < 4; ++j) {
        const int s = j * 16 + fr;
        const float cs = scum[s], ds = sdt[s];
#pragma unroll
        for (int r = 0; r < 4; ++r) {
            const int t = trow + r;
            const float m = (s <= t) ? g[j][r] * __expf(ct[r] - cs) * ds : 0.f;
            sM[t][s] = f2bf(m);
        }
    }
    __syncthreads();

    // --- Y1 = M.X, Y2 = C.SP ---
    short8 aM0 = *(const short8*)&sM[w * 16 + fr][ko];
    short8 aM1 = *(const short8*)&sM[w * 16 + fr][ko + 32];
    f32x4 y1[4], y2[4];
#pragma unroll
    for (int j = 0; j < 4; ++j) {
        short8 bx0 = *(const short8*)&sXT[j * 16 + fr][ko];
        short8 bx1 = *(const short8*)&sXT[j * 16 + fr][ko + 32];
        f32x4 a = (f32x4){0.f, 0.f, 0.f, 0.f};
        a = MFMA_BF16(aM0, bx0, a, 0, 0, 0);
        a = MFMA_BF16(aM1, bx1, a, 0, 0, 0);
        y1[j] = a;
        short8 bs0 = *(const short8*)&sSPT[j * 16 + fr][ko];
        short8 bs1 = *(const short8*)&sSPT[j * 16 + fr][ko + 32];
        f32x4 a2 = (f32x4){0.f, 0.f, 0.f, 0.f};
        a2 = MFMA_BF16(aC0, bs0, a2, 0, 0, 0);
        a2 = MFMA_BF16(aC1, bs1, a2, 0, 0, 0);
        y2[j] = a2;
    }

    const float Dp = D_param[h];
    float et[4];
#pragma unroll
    for (int r = 0; r < 4; ++r) et[r] = __expf(ct[r]);
    unsigned short* ybase = y + (((size_t)b * SEQLEN + c * QCHUNK) * D_INNER) + h * HEADDIM;
#pragma unroll
    for (int j = 0; j < 4; ++j) {
        const int p = j * 16 + fr;
#pragma unroll
        for (int r = 0; r < 4; ++r) {
            const int t = trow + r;
            const float xv = bf2f(sXT[p][t]);
            ybase[(size_t)t * D_INNER + p] = f2bf(y1[j][r] + et[r] * y2[j][r] + Dp * xv);
        }
    }
}

// ---------------------------------------------------------------------------
// RMSNorm * norm_w * silu(z) -> bf16; y and z read as bf16
// ---------------------------------------------------------------------------
__global__ __launch_bounds__(256) void rms_gate_kernel(
    const unsigned short* __restrict__ y, const unsigned short* __restrict__ zxb,
    const float* __restrict__ norm_w, unsigned short* __restrict__ out)
{
    const int m = blockIdx.x;
    const int tid = threadIdx.x;
    const unsigned short* yr = y + (size_t)m * D_INNER;
    const unsigned short* zr = zxb + (size_t)m * ZXLD;

    ushort8v yv8 = *(const ushort8v*)(yr + tid * 8);
    float yv[8];
#pragma unroll
    for (int j = 0; j < 8; ++j) yv[j] = bf2f(yv8[j]);
    float ss = 0.f;
#pragma unroll
    for (int j = 0; j < 8; ++j) ss += yv[j] * yv[j];
#pragma unroll
    for (int off = 32; off > 0; off >>= 1) ss += __shfl_xor(ss, off, 64);
    __shared__ float sred[4];
    if ((tid & 63) == 0) sred[tid >> 6] = ss;
    __syncthreads();
    const float tot = sred[0] + sred[1] + sred[2] + sred[3];
    const float inv = rsqrtf(tot * (1.f / D_INNER) + RMS_EPS);

    ushort8v zv8 = *(const ushort8v*)(zr + tid * 8);
    const float* nw = norm_w + tid * 8;
    ushort8v o;
#pragma unroll
    for (int j = 0; j < 8; ++j) {
        const float zz = bf2f(zv8[j]);
        const float sig = 1.f / (1.f + __expf(-zz));
        o[j] = f2bf(yv[j] * inv * nw[j] * (zz * sig));
    }
    *(ushort8v*)(out + (size_t)m * D_INNER + tid * 8) = o;
}

// ---------------------------------------------------------------------------
// Workspace layout (~70 MB)
// ---------------------------------------------------------------------------
extern "C" void kernel_launch(void* const* d_in, const int* in_sizes, int n_in,
                              void* d_out, int out_size, void* d_ws, size_t ws_size,
                              hipStream_t stream)
{
    const float* x       = (const float*)d_in[0];
    const float* W_in    = (const float*)d_in[1];
    const float* conv_w  = (const float*)d_in[2];
    const float* conv_b  = (const float*)d_in[3];
    const float* dt_bias = (const float*)d_in[4];
    const float* A_log   = (const float*)d_in[5];
    const float* D_param = (const float*)d_in[6];
    const float* norm_w  = (const float*)d_in[7];
    const float* W_out   = (const float*)d_in[8];
    float* out = (float*)d_out;

    char* p = (char*)d_ws;
    unsigned short* zxb   = (unsigned short*)p;  p += (size_t)BL * ZXLD * 2;
    float*          dtt   = (float*)p;           p += (size_t)BATCH * NHEADS * SEQLEN * 4;
    float*          cumA  = (float*)p;           p += (size_t)BATCH * NHEADS * SEQLEN * 4;
    unsigned short* Sb    = (unsigned short*)p;  p += (size_t)BATCH * NHEADS * NC * 4096 * 2;
    unsigned short* xTb   = (unsigned short*)p;  p += (size_t)BATCH * NHEADS * NC * 4096 * 2;
    unsigned short* Bcc   = (unsigned short*)p;  p += (size_t)BATCH * NC * 4096 * 2;
    unsigned short* BTc   = (unsigned short*)p;  p += (size_t)BATCH * NC * 4096 * 2;
    unsigned short* Ccc   = (unsigned short*)p;  p += (size_t)BATCH * NC * 4096 * 2;
    unsigned short* ybb   = (unsigned short*)p;  p += (size_t)BL * D_INNER * 2;
    unsigned short* xb    = (unsigned short*)p;  p += (size_t)BL * D_MODEL * 2;
    unsigned short* winb  = (unsigned short*)p;  p += (size_t)ZXLD * D_MODEL * 2;
    unsigned short* woutb = (unsigned short*)p;  p += (size_t)D_MODEL * D_INNER * 2;
    unsigned short* ygb   = (unsigned short*)p;

    // 0) casts
    cast_bf16_kernel<<<(BL * D_MODEL / 4 + 255) / 256, 256, 0, stream>>>(
        x, xb, BL * D_MODEL / 4);
    cast_win_pad_kernel<<<(ZXLD * D_MODEL / 4 + 255) / 256, 256, 0, stream>>>(W_in, winb);
    cast_bf16_kernel<<<(D_MODEL * D_INNER / 4 + 255) / 256, 256, 0, stream>>>(
        W_out, woutb, D_MODEL * D_INNER / 4);

    // 1) in_proj (bf16 MFMA -> bf16 zx)
    gemm_bf16_nt<128, 128, 2, 2, true><<<dim3(ZXLD / 128, BL / 128), 256, 0, stream>>>(
        xb, winb, zxb, D_MODEL, ZXLD);

    // 2) dt softplus
    dt_softplus_kernel<<<(BL * NHEADS) / 256, 256, 0, stream>>>(zxb, dt_bias, dtt);
    // 3) conv+silu single pass -> chunk-tile layouts
    conv_pre_kernel<<<dim3(NC, 17, BATCH), 256, 0, stream>>>(
        zxb, conv_w, conv_b, xTb, Bcc, BTc, Ccc);
    // 4) chunked SSM scan
    chunk_state_kernel<<<BATCH * NHEADS * NC, 256, 0, stream>>>(
        xTb, BTc, dtt, A_log, Sb, cumA);
    state_pass_kernel<<<256, 256, 0, stream>>>(Sb, cumA);
    chunk_output_kernel<<<BATCH * NHEADS * NC, 256, 0, stream>>>(
        xTb, Bcc, Ccc, dtt, Sb, cumA, D_param, ybb);
    // 5) RMSNorm + gate -> bf16
    rms_gate_kernel<<<BL, 256, 0, stream>>>(ybb, zxb, norm_w, ygb);

    // 6) out_proj (bf16 MFMA -> fp32 out)
    gemm_bf16_nt<64, 128, 1, 4, false><<<dim3(D_MODEL / 128, BL / 64), 256, 0, stream>>>(
        ygb, woutb, out, D_INNER, D_MODEL);
}

// Round 7
// 113.921 us; speedup vs baseline: 10.4739x; 1.1922x over previous
//
#include <hip/hip_runtime.h>
#include <hip/hip_bf16.h>
#include <math.h>

// Problem dims
#define D_MODEL   1024
#define D_INNER   2048
#define NHEADS    32
#define HEADDIM   64
#define D_STATE   64
#define CONV_DIM  2176            // D_INNER + 2*D_STATE
#define D_IN_PROJ 4256            // 2*D_INNER + 2*D_STATE + NHEADS
#define ZXLD      4352            // padded to 128
#define BATCH     2
#define SEQLEN    1024
#define BL        (BATCH * SEQLEN)
#define RMS_EPS   1.1920929e-07f

#define QCHUNK 64
#define NC     (SEQLEN / QCHUNK)

typedef __attribute__((ext_vector_type(8))) short short8;
typedef __attribute__((ext_vector_type(4))) float f32x4;
typedef __attribute__((ext_vector_type(8))) unsigned short ushort8v;
typedef __attribute__((ext_vector_type(4))) unsigned short ushort4v;

__device__ __forceinline__ unsigned short f2bf(float f) {
    unsigned u = __builtin_bit_cast(unsigned, f);
    unsigned r = u + 0x7FFFu + ((u >> 16) & 1u);   // RTNE
    return (unsigned short)(r >> 16);
}
__device__ __forceinline__ float bf2f(unsigned short u) {
    unsigned v = ((unsigned)u) << 16;
    return __builtin_bit_cast(float, v);
}
__device__ __forceinline__ void gload_lds16(const void* g, void* l) {
    __builtin_amdgcn_global_load_lds(
        (const __attribute__((address_space(1))) void*)g,
        (__attribute__((address_space(3))) void*)l, 16, 0, 0);
}

#define MFMA_BF16 __builtin_amdgcn_mfma_f32_16x16x32_bf16

// ---------------------------------------------------------------------------
// bf16 MFMA GEMM, NT: C[m,n] = sum_k A[m,k]*B[n,k].  BK=64.
// LDS rows are 128B (64 bf16 = 8 slots of 16B). Swizzle (both-sides, rule#21):
//   LDS[row][slot] holds global element (row, slot ^ (row&7));
//   global_load_lds dest stays LINEAR; the global SOURCE slot is permuted;
//   ds_read applies the same XOR -> 2 lanes/bank (conflict-free).
// ---------------------------------------------------------------------------
template<int BM, int BN, int WR, int WC, bool OBF16>
__global__ __launch_bounds__(256) void gemm_bf16_nt(
    const unsigned short* __restrict__ A, const unsigned short* __restrict__ B,
    void* __restrict__ Cv, int K, int ldc)
{
    constexpr int RM = BM / WR;
    constexpr int RN = BN / WC;
    constexpr int MF = RM / 16;
    constexpr int NF = RN / 16;
    constexpr int GA = BM / 32;    // wave-loads per wave for A (1KB each)
    constexpr int GB = BN / 32;

    __shared__ unsigned short As[BM][64];
    __shared__ unsigned short Bs[BN][64];

    const int tid  = threadIdx.x;
    const int lane = tid & 63;
    const int w    = tid >> 6;
    const int wm   = w / WC;
    const int wn   = w % WC;
    const int m0   = blockIdx.y * BM;
    const int n0   = blockIdx.x * BN;

    // staging lane geometry: 8 lanes per row, swizzled source slot
    const int srow  = lane >> 3;                 // 0..7 row within 8-row group
    const int sslot = (lane & 7) ^ srow;         // pre-swizzled global slot

    const int fr  = lane & 15;
    const int h   = lane >> 4;
    const int fr7 = fr & 7;

    f32x4 acc[MF][NF];
#pragma unroll
    for (int mi = 0; mi < MF; ++mi)
#pragma unroll
        for (int ni = 0; ni < NF; ++ni) acc[mi][ni] = (f32x4){0.f, 0.f, 0.f, 0.f};

    for (int k0 = 0; k0 < K; k0 += 64) {
        __syncthreads();
#pragma unroll
        for (int q = 0; q < GA; ++q) {
            const int g8 = (w * GA + q) * 8;
            const unsigned short* gp =
                A + (size_t)(m0 + g8 + srow) * K + k0 + sslot * 8;
            gload_lds16(gp, &As[g8][0]);
        }
#pragma unroll
        for (int q = 0; q < GB; ++q) {
            const int g8 = (w * GB + q) * 8;
            const unsigned short* gp =
                B + (size_t)(n0 + g8 + srow) * K + k0 + sslot * 8;
            gload_lds16(gp, &Bs[g8][0]);
        }
        __syncthreads();

#pragma unroll
        for (int ks = 0; ks < 2; ++ks) {
            const int slot = (ks * 4 + h) ^ fr7;   // swizzled read slot
            short8 av[MF], bv[NF];
#pragma unroll
            for (int mi = 0; mi < MF; ++mi)
                av[mi] = *(const short8*)&As[wm * RM + mi * 16 + fr][slot * 8];
#pragma unroll
            for (int ni = 0; ni < NF; ++ni)
                bv[ni] = *(const short8*)&Bs[wn * RN + ni * 16 + fr][slot * 8];
#pragma unroll
            for (int mi = 0; mi < MF; ++mi)
#pragma unroll
                for (int ni = 0; ni < NF; ++ni)
                    acc[mi][ni] = MFMA_BF16(av[mi], bv[ni], acc[mi][ni], 0, 0, 0);
        }
    }

    const int crow = (lane >> 4) * 4;
    const int ccol = lane & 15;
#pragma unroll
    for (int mi = 0; mi < MF; ++mi)
#pragma unroll
        for (int ni = 0; ni < NF; ++ni) {
            const int row0 = m0 + wm * RM + mi * 16 + crow;
            const int col  = n0 + wn * RN + ni * 16 + ccol;
#pragma unroll
            for (int r = 0; r < 4; ++r) {
                if constexpr (OBF16) {
                    ((unsigned short*)Cv)[(size_t)(row0 + r) * ldc + col] =
                        f2bf(acc[mi][ni][r]);
                } else {
                    ((float*)Cv)[(size_t)(row0 + r) * ldc + col] = acc[mi][ni][r];
                }
            }
        }
}

// ---------------------------------------------------------------------------
// fp32 -> bf16 casts
// ---------------------------------------------------------------------------
__global__ __launch_bounds__(256) void cast_bf16_kernel(
    const float* __restrict__ src, unsigned short* __restrict__ dst, int n4)
{
    const int i = (blockIdx.x * 256 + threadIdx.x);
    if (i >= n4) return;
    float4 v = *(const float4*)(src + (size_t)i * 4);
    ushort4 o;
    o.x = f2bf(v.x); o.y = f2bf(v.y); o.z = f2bf(v.z); o.w = f2bf(v.w);
    *(ushort4*)(dst + (size_t)i * 4) = o;
}

__global__ __launch_bounds__(256) void cast_win_pad_kernel(
    const float* __restrict__ src, unsigned short* __restrict__ dst)
{
    const int i = (blockIdx.x * 256 + threadIdx.x);
    if (i >= ZXLD * D_MODEL / 4) return;
    const int e0 = i * 4;
    const int row = e0 >> 10;
    ushort4 o = {0, 0, 0, 0};
    if (row < D_IN_PROJ) {
        float4 v = *(const float4*)(src + (size_t)e0);
        o.x = f2bf(v.x); o.y = f2bf(v.y); o.z = f2bf(v.z); o.w = f2bf(v.w);
    }
    *(ushort4*)(dst + (size_t)e0) = o;
}

// ---------------------------------------------------------------------------
// dt = softplus(dt_raw + dt_bias) from bf16 zx, transposed: dtt[b][h][l]
// ---------------------------------------------------------------------------
__global__ __launch_bounds__(256) void dt_softplus_kernel(
    const unsigned short* __restrict__ zxb, const float* __restrict__ dt_bias,
    float* __restrict__ dtt)
{
    const int idx = blockIdx.x * 256 + threadIdx.x;
    const int m = idx >> 5;
    const int hd = idx & 31;
    const int b = m >> 10;
    const int l = m & (SEQLEN - 1);
    const float v = bf2f(zxb[(size_t)m * ZXLD + (D_INNER + CONV_DIM) + hd]) + dt_bias[hd];
    const float sp = (v > 20.f) ? v : log1pf(__expf(v));
    dtt[((size_t)b * NHEADS + hd) * SEQLEN + l] = sp;
}

// ---------------------------------------------------------------------------
// conv_pre: single-pass conv(4-tap causal)+silu over the conv strip of zxb.
// Emits bf16 in the layouts the chunk kernels consume.
// grid (NC, 17, BATCH): g<16 -> x channels (heads 2g,2g+1); g==16 -> B,C.
// ---------------------------------------------------------------------------
__global__ __launch_bounds__(256) void conv_pre_kernel(
    const unsigned short* __restrict__ zxb,
    const float* __restrict__ conv_w, const float* __restrict__ conv_b,
    unsigned short* __restrict__ xTb, unsigned short* __restrict__ Bcc,
    unsigned short* __restrict__ BTc, unsigned short* __restrict__ Ccc)
{
    const int c = blockIdx.x;
    const int g = blockIdx.y;
    const int b = blockIdx.z;
    const int tid = threadIdx.x;

    __shared__ unsigned short L[64][138];

    const int l0 = c * QCHUNK;
    const int grow0 = b * SEQLEN + l0;
    const int r = tid >> 2;             // row t within chunk
    const int q = (tid & 3) * 16;       // channel offset within 64-ch half

    for (int hh = 0; hh < 2; ++hh) {
        const int chbase = g * 128 + hh * 64;
        float in[4][16];
#pragma unroll
        for (int k = 0; k < 4; ++k) {
            const int ll = l0 + r - 3 + k;
            if (ll >= 0) {
                const unsigned short* src =
                    zxb + (size_t)(grow0 + r - 3 + k) * ZXLD + (D_INNER + chbase + q);
                ushort8v v0 = *(const ushort8v*)(src);
                ushort8v v1 = *(const ushort8v*)(src + 8);
#pragma unroll
                for (int j = 0; j < 8; ++j) { in[k][j] = bf2f(v0[j]); in[k][8 + j] = bf2f(v1[j]); }
            } else {
#pragma unroll
                for (int j = 0; j < 16; ++j) in[k][j] = 0.f;
            }
        }
        unsigned short o[16];
#pragma unroll
        for (int j = 0; j < 16; ++j) {
            const int ch = chbase + q + j;
            const float4 wv = *(const float4*)(conv_w + ch * 4);
            float a = conv_b[ch];
            a = fmaf(in[0][j], wv.x, a);
            a = fmaf(in[1][j], wv.y, a);
            a = fmaf(in[2][j], wv.z, a);
            a = fmaf(in[3][j], wv.w, a);
            o[j] = f2bf(a / (1.f + __expf(-a)));
        }

        const bool isB = (g == 16) && (hh == 0);
        const bool isC = (g == 16) && (hh == 1);
        const size_t ctile = ((size_t)b * NC + c) * 4096;

        if (isB || isC) {
            unsigned short* dst = (isB ? Bcc : Ccc) + ctile + (size_t)r * 64 + q;
            ushort8v w0, w1;
#pragma unroll
            for (int j = 0; j < 8; ++j) { w0[j] = o[j]; w1[j] = o[8 + j]; }
            *(ushort8v*)dst = w0;
            *(ushort8v*)(dst + 8) = w1;
        }
        if (!isC) {
#pragma unroll
            for (int j = 0; j < 8; ++j) { L[r][q + j] = o[j]; L[r][q + 8 + j] = o[8 + j]; }
            __syncthreads();
            const int cc = tid >> 2;
            const int tseg = (tid & 3) * 16;
            unsigned short tv[16];
#pragma unroll
            for (int j = 0; j < 16; ++j) tv[j] = L[tseg + j][cc];
            unsigned short* dstT;
            if (isB) dstT = BTc + ctile + (size_t)cc * 64 + tseg;
            else {
                const int hgt = g * 2 + hh;
                dstT = xTb + (((size_t)b * NHEADS + hgt) * NC + c) * 4096 + (size_t)cc * 64 + tseg;
            }
            ushort8v w0, w1;
#pragma unroll
            for (int j = 0; j < 8; ++j) { w0[j] = tv[j]; w1[j] = tv[8 + j]; }
            *(ushort8v*)dstT = w0;
            *(ushort8v*)(dstT + 8) = w1;
        }
        __syncthreads();
    }
}

// ---------------------------------------------------------------------------
// Phase A (MFMA): S[n,p] = sum_t B[t,n] * (w_t*X[t,p]); identity staging.
// ---------------------------------------------------------------------------
__global__ __launch_bounds__(256) void chunk_state_kernel(
    const unsigned short* __restrict__ xTb, const unsigned short* __restrict__ BTc,
    const float* __restrict__ dtt, const float* __restrict__ A_log,
    unsigned short* __restrict__ Sintra, float* __restrict__ cumA)
{
    const int bid = blockIdx.x;
    const int c = bid & (NC - 1);
    const int h = (bid >> 4) & (NHEADS - 1);
    const int b = bid >> 9;
    const int tid = threadIdx.x;
    const int lane = tid & 63;
    const int w = tid >> 6;

    __shared__ unsigned short sXT[64][72];
    __shared__ unsigned short sBT[64][72];
    __shared__ float sw[64];

    if (tid < QCHUNK) {
        const float A = -__expf(A_log[h]);
        const float dtv = dtt[((size_t)b * NHEADS + h) * SEQLEN + c * QCHUNK + tid];
        float cum = dtv * A;
#pragma unroll
        for (int off = 1; off < 64; off <<= 1) {
            const float o = __shfl_up(cum, off, 64);
            if (tid >= off) cum += o;
        }
        const float cum_end = __shfl(cum, 63, 64);
        sw[tid] = __expf(cum_end - cum) * dtv;
        cumA[(size_t)bid * QCHUNK + tid] = cum;
    }
    __syncthreads();

    {
        const int r = tid >> 2, q = (tid & 3) * 16;
        const unsigned short* xs =
            xTb + (((size_t)b * NHEADS + h) * NC + c) * 4096 + (size_t)r * 64 + q;
        ushort8v v0 = *(const ushort8v*)(xs);
        ushort8v v1 = *(const ushort8v*)(xs + 8);
        ushort8v s0, s1;
#pragma unroll
        for (int j = 0; j < 8; ++j) {
            s0[j] = f2bf(bf2f(v0[j]) * sw[q + j]);
            s1[j] = f2bf(bf2f(v1[j]) * sw[q + 8 + j]);
        }
        *(ushort8v*)&sXT[r][q] = s0;
        *(ushort8v*)&sXT[r][q + 8] = s1;

        const unsigned short* bs =
            BTc + ((size_t)b * NC + c) * 4096 + (size_t)r * 64 + q;
        *(ushort8v*)&sBT[r][q]     = *(const ushort8v*)(bs);
        *(ushort8v*)&sBT[r][q + 8] = *(const ushort8v*)(bs + 8);
    }
    __syncthreads();

    const int fr = lane & 15;
    const int ko = (lane >> 4) * 8;
    short8 a0 = *(const short8*)&sBT[w * 16 + fr][ko];
    short8 a1 = *(const short8*)&sBT[w * 16 + fr][ko + 32];

    unsigned short* sout = Sintra + (size_t)bid * (D_STATE * HEADDIM);
    const int nrow = w * 16 + (lane >> 4) * 4;
#pragma unroll
    for (int j = 0; j < 4; ++j) {
        short8 b0 = *(const short8*)&sXT[j * 16 + fr][ko];
        short8 b1 = *(const short8*)&sXT[j * 16 + fr][ko + 32];
        f32x4 a = (f32x4){0.f, 0.f, 0.f, 0.f};
        a = MFMA_BF16(a0, b0, a, 0, 0, 0);
        a = MFMA_BF16(a1, b1, a, 0, 0, 0);
        const int p = j * 16 + fr;
#pragma unroll
        for (int r = 0; r < 4; ++r)
            sout[(size_t)(nrow + r) * HEADDIM + p] = f2bf(a[r]);
    }
}

// ---------------------------------------------------------------------------
// Phase B: inter-chunk recurrence on bf16 S (elementwise, 256 blocks)
// ---------------------------------------------------------------------------
__global__ __launch_bounds__(256) void state_pass_kernel(
    unsigned short* __restrict__ S, const float* __restrict__ cumA)
{
    const int gid = blockIdx.x * 256 + threadIdx.x;
    const int bh = gid >> 10;
    const int e0 = (gid & 1023) * 4;

    float run[4] = {0.f, 0.f, 0.f, 0.f};
    unsigned short* base = S + (size_t)bh * NC * (D_STATE * HEADDIM) + e0;

    ushort4v pre = *(const ushort4v*)base;
    float gpre = __expf(cumA[((size_t)bh * NC) * QCHUNK + (QCHUNK - 1)]);

    for (int c = 0; c < NC; ++c) {
        const ushort4v cur = pre;
        const float g = gpre;
        if (c + 1 < NC) {
            pre = *(const ushort4v*)(base + (size_t)(c + 1) * (D_STATE * HEADDIM));
            gpre = __expf(cumA[((size_t)bh * NC + c + 1) * QCHUNK + (QCHUNK - 1)]);
        }
        ushort4v o;
#pragma unroll
        for (int j = 0; j < 4; ++j) o[j] = f2bf(run[j]);
        *(ushort4v*)(base + (size_t)c * (D_STATE * HEADDIM)) = o;
#pragma unroll
        for (int j = 0; j < 4; ++j) run[j] = fmaf(g, run[j], bf2f(cur[j]));
    }
}

// ---------------------------------------------------------------------------
// Phase C (MFMA): G = C.B^T; M = mask(G)*exp(dcum)*dt; Y = M.X + exp(cum)*C.SP + D*x
// ---------------------------------------------------------------------------
__global__ __launch_bounds__(256) void chunk_output_kernel(
    const unsigned short* __restrict__ xTb, const unsigned short* __restrict__ Bcc,
    const unsigned short* __restrict__ Ccc, const float* __restrict__ dtt,
    const unsigned short* __restrict__ SP, const float* __restrict__ cumA,
    const float* __restrict__ D_param, unsigned short* __restrict__ y)
{
    const int bid = blockIdx.x;
    const int c = bid & (NC - 1);
    const int h = (bid >> 4) & (NHEADS - 1);
    const int b = bid >> 9;
    const int tid = threadIdx.x;
    const int lane = tid & 63;
    const int w = tid >> 6;

    __shared__ unsigned short sC[64][72];
    __shared__ unsigned short sB[64][72];
    __shared__ unsigned short sXT[64][72];
    __shared__ unsigned short sSPT[64][72];
    __shared__ unsigned short sM[64][72];
    __shared__ float scum[64], sdt[64];

    const size_t ctile = ((size_t)b * NC + c) * 4096;
    {
        const int r = tid >> 2, q = (tid & 3) * 16;
        const unsigned short* cs = Ccc + ctile + (size_t)r * 64 + q;
        *(ushort8v*)&sC[r][q]     = *(const ushort8v*)(cs);
        *(ushort8v*)&sC[r][q + 8] = *(const ushort8v*)(cs + 8);
        const unsigned short* bs = Bcc + ctile + (size_t)r * 64 + q;
        *(ushort8v*)&sB[r][q]     = *(const ushort8v*)(bs);
        *(ushort8v*)&sB[r][q + 8] = *(const ushort8v*)(bs + 8);
        const unsigned short* xs =
            xTb + (((size_t)b * NHEADS + h) * NC + c) * 4096 + (size_t)r * 64 + q;
        *(ushort8v*)&sXT[r][q]     = *(const ushort8v*)(xs);
        *(ushort8v*)&sXT[r][q + 8] = *(const ushort8v*)(xs + 8);
        const unsigned short* ss = SP + (size_t)bid * (D_STATE * HEADDIM) + (size_t)r * 64 + q;
        ushort8v v0 = *(const ushort8v*)(ss);
        ushort8v v1 = *(const ushort8v*)(ss + 8);
#pragma unroll
        for (int j = 0; j < 8; ++j) { sSPT[q + j][r] = v0[j]; sSPT[q + 8 + j][r] = v1[j]; }
    }
    if (tid < QCHUNK) {
        scum[tid] = cumA[(size_t)bid * QCHUNK + tid];
        sdt[tid] = dtt[((size_t)b * NHEADS + h) * SEQLEN + c * QCHUNK + tid];
    }
    __syncthreads();

    const int fr = lane & 15;
    const int ko = (lane >> 4) * 8;
    const int trow = w * 16 + (lane >> 4) * 4;

    short8 aC0 = *(const short8*)&sC[w * 16 + fr][ko];
    short8 aC1 = *(const short8*)&sC[w * 16 + fr][ko + 32];

    f32x4 g[4];
#pragma unroll
    for (int j = 0; j < 4; ++j) {
        short8 b0 = *(const short8*)&sB[j * 16 + fr][ko];
        short8 b1 = *(const short8*)&sB[j * 16 + fr][ko + 32];
        f32x4 a = (f32x4){0.f, 0.f, 0.f, 0.f};
        a = MFMA_BF16(aC0, b0, a, 0, 0, 0);
        a = MFMA_BF16(aC1, b1, a, 0, 0, 0);
        g[j] = a;
    }

    float ct[4];
#pragma unroll
    for (int r = 0; r < 4; ++r) ct[r] = scum[trow + r];
#pragma unroll
    for (int j = 0; j < 4; ++j) {
        const int s = j * 16 + fr;
        const float cs = scum[s], ds = sdt[s];
#pragma unroll
        for (int r = 0; r < 4; ++r) {
            const int t = trow + r;
            const float m = (s <= t) ? g[j][r] * __expf(ct[r] - cs) * ds : 0.f;
            sM[t][s] = f2bf(m);
        }
    }
    __syncthreads();

    short8 aM0 = *(const short8*)&sM[w * 16 + fr][ko];
    short8 aM1 = *(const short8*)&sM[w * 16 + fr][ko + 32];
    f32x4 y1[4], y2[4];
#pragma unroll
    for (int j = 0; j < 4; ++j) {
        short8 bx0 = *(const short8*)&sXT[j * 16 + fr][ko];
        short8 bx1 = *(const short8*)&sXT[j * 16 + fr][ko + 32];
        f32x4 a = (f32x4){0.f, 0.f, 0.f, 0.f};
        a = MFMA_BF16(aM0, bx0, a, 0, 0, 0);
        a = MFMA_BF16(aM1, bx1, a, 0, 0, 0);
        y1[j] = a;
        short8 bs0 = *(const short8*)&sSPT[j * 16 + fr][ko];
        short8 bs1 = *(const short8*)&sSPT[j * 16 + fr][ko + 32];
        f32x4 a2 = (f32x4){0.f, 0.f, 0.f, 0.f};
        a2 = MFMA_BF16(aC0, bs0, a2, 0, 0, 0);
        a2 = MFMA_BF16(aC1, bs1, a2, 0, 0, 0);
        y2[j] = a2;
    }

    const float Dp = D_param[h];
    float et[4];
#pragma unroll
    for (int r = 0; r < 4; ++r) et[r] = __expf(ct[r]);
    unsigned short* ybase = y + (((size_t)b * SEQLEN + c * QCHUNK) * D_INNER) + h * HEADDIM;
#pragma unroll
    for (int j = 0; j < 4; ++j) {
        const int p = j * 16 + fr;
#pragma unroll
        for (int r = 0; r < 4; ++r) {
            const int t = trow + r;
            const float xv = bf2f(sXT[p][t]);
            ybase[(size_t)t * D_INNER + p] = f2bf(y1[j][r] + et[r] * y2[j][r] + Dp * xv);
        }
    }
}

// ---------------------------------------------------------------------------
// RMSNorm * norm_w * silu(z) -> bf16; y and z read as bf16
// ---------------------------------------------------------------------------
__global__ __launch_bounds__(256) void rms_gate_kernel(
    const unsigned short* __restrict__ y, const unsigned short* __restrict__ zxb,
    const float* __restrict__ norm_w, unsigned short* __restrict__ out)
{
    const int m = blockIdx.x;
    const int tid = threadIdx.x;
    const unsigned short* yr = y + (size_t)m * D_INNER;
    const unsigned short* zr = zxb + (size_t)m * ZXLD;

    ushort8v yv8 = *(const ushort8v*)(yr + tid * 8);
    float yv[8];
#pragma unroll
    for (int j = 0; j < 8; ++j) yv[j] = bf2f(yv8[j]);
    float ss = 0.f;
#pragma unroll
    for (int j = 0; j < 8; ++j) ss += yv[j] * yv[j];
#pragma unroll
    for (int off = 32; off > 0; off >>= 1) ss += __shfl_xor(ss, off, 64);
    __shared__ float sred[4];
    if ((tid & 63) == 0) sred[tid >> 6] = ss;
    __syncthreads();
    const float tot = sred[0] + sred[1] + sred[2] + sred[3];
    const float inv = rsqrtf(tot * (1.f / D_INNER) + RMS_EPS);

    ushort8v zv8 = *(const ushort8v*)(zr + tid * 8);
    const float* nw = norm_w + tid * 8;
    ushort8v o;
#pragma unroll
    for (int j = 0; j < 8; ++j) {
        const float zz = bf2f(zv8[j]);
        const float sig = 1.f / (1.f + __expf(-zz));
        o[j] = f2bf(yv[j] * inv * nw[j] * (zz * sig));
    }
    *(ushort8v*)(out + (size_t)m * D_INNER + tid * 8) = o;
}

// ---------------------------------------------------------------------------
// Workspace layout (~70 MB)
// ---------------------------------------------------------------------------
extern "C" void kernel_launch(void* const* d_in, const int* in_sizes, int n_in,
                              void* d_out, int out_size, void* d_ws, size_t ws_size,
                              hipStream_t stream)
{
    const float* x       = (const float*)d_in[0];
    const float* W_in    = (const float*)d_in[1];
    const float* conv_w  = (const float*)d_in[2];
    const float* conv_b  = (const float*)d_in[3];
    const float* dt_bias = (const float*)d_in[4];
    const float* A_log   = (const float*)d_in[5];
    const float* D_param = (const float*)d_in[6];
    const float* norm_w  = (const float*)d_in[7];
    const float* W_out   = (const float*)d_in[8];
    float* out = (float*)d_out;

    char* p = (char*)d_ws;
    unsigned short* zxb   = (unsigned short*)p;  p += (size_t)BL * ZXLD * 2;
    float*          dtt   = (float*)p;           p += (size_t)BATCH * NHEADS * SEQLEN * 4;
    float*          cumA  = (float*)p;           p += (size_t)BATCH * NHEADS * SEQLEN * 4;
    unsigned short* Sb    = (unsigned short*)p;  p += (size_t)BATCH * NHEADS * NC * 4096 * 2;
    unsigned short* xTb   = (unsigned short*)p;  p += (size_t)BATCH * NHEADS * NC * 4096 * 2;
    unsigned short* Bcc   = (unsigned short*)p;  p += (size_t)BATCH * NC * 4096 * 2;
    unsigned short* BTc   = (unsigned short*)p;  p += (size_t)BATCH * NC * 4096 * 2;
    unsigned short* Ccc   = (unsigned short*)p;  p += (size_t)BATCH * NC * 4096 * 2;
    unsigned short* ybb   = (unsigned short*)p;  p += (size_t)BL * D_INNER * 2;
    unsigned short* xb    = (unsigned short*)p;  p += (size_t)BL * D_MODEL * 2;
    unsigned short* winb  = (unsigned short*)p;  p += (size_t)ZXLD * D_MODEL * 2;
    unsigned short* woutb = (unsigned short*)p;  p += (size_t)D_MODEL * D_INNER * 2;
    unsigned short* ygb   = (unsigned short*)p;

    // 0) casts
    cast_bf16_kernel<<<(BL * D_MODEL / 4 + 255) / 256, 256, 0, stream>>>(
        x, xb, BL * D_MODEL / 4);
    cast_win_pad_kernel<<<(ZXLD * D_MODEL / 4 + 255) / 256, 256, 0, stream>>>(W_in, winb);
    cast_bf16_kernel<<<(D_MODEL * D_INNER / 4 + 255) / 256, 256, 0, stream>>>(
        W_out, woutb, D_MODEL * D_INNER / 4);

    // 1) in_proj (bf16 MFMA -> bf16 zx), 128x128 tile, BK=64, 544 blocks
    gemm_bf16_nt<128, 128, 2, 2, true><<<dim3(ZXLD / 128, BL / 128), 256, 0, stream>>>(
        xb, winb, zxb, D_MODEL, ZXLD);

    // 2) dt softplus
    dt_softplus_kernel<<<(BL * NHEADS) / 256, 256, 0, stream>>>(zxb, dt_bias, dtt);
    // 3) conv+silu single pass -> chunk-tile layouts
    conv_pre_kernel<<<dim3(NC, 17, BATCH), 256, 0, stream>>>(
        zxb, conv_w, conv_b, xTb, Bcc, BTc, Ccc);
    // 4) chunked SSM scan
    chunk_state_kernel<<<BATCH * NHEADS * NC, 256, 0, stream>>>(
        xTb, BTc, dtt, A_log, Sb, cumA);
    state_pass_kernel<<<256, 256, 0, stream>>>(Sb, cumA);
    chunk_output_kernel<<<BATCH * NHEADS * NC, 256, 0, stream>>>(
        xTb, Bcc, Ccc, dtt, Sb, cumA, D_param, ybb);
    // 5) RMSNorm + gate -> bf16
    rms_gate_kernel<<<BL, 256, 0, stream>>>(ybb, zxb, norm_w, ygb);

    // 6) out_proj (bf16 MFMA -> fp32 out), 64x64 tile, BK=64, 512 blocks
    gemm_bf16_nt<64, 64, 2, 2, false><<<dim3(D_MODEL / 64, BL / 64), 256, 0, stream>>>(
        ygb, woutb, out, D_INNER, D_MODEL);
}